// Round 1
// 1286.910 us; speedup vs baseline: 1.3723x; 1.3723x over previous
//
#include <hip/hip_runtime.h>
#include <cstdint>
#include <cstddef>

#define NN 100000
#define EE 1600000
#define XDIM 1553
#define HD 128

typedef __attribute__((ext_vector_type(8))) short short8;
typedef __attribute__((ext_vector_type(4))) float f32x4;

union Frag { unsigned int u[4]; short8 s; uint4 v; };

// weight area offsets (ushort units); hi/lo are separate regions
#define OFF_DES_HI 0
#define OFF_DES_LO 98304
#define OFF_TW_HI  196608
#define OFF_TW_LO  294912
#define OFF_NUM_HI 393216
#define OFF_NUM_LO 397312
#define OFF_CAT_HI 401408
#define OFF_CAT_LO 405504
#define OFF_WIN_HI 409600
#define OFF_WIN_LO 475136
#define OFF_L1_HI  540672
#define OFF_L1_LO  589824
#define OFF_L2_HI  638976
#define OFF_L2_LO  688128
#define OFF_CLS_HI 737280
#define OFF_CLS_LO 753664
#define WT_SITES   385024   // (col,k) sites; each writes hi+lo

// hi = trunc-bf16(f), lo = trunc-bf16(f - hi). Packed: 2 elems -> 1 u32 via v_perm.
__device__ __forceinline__ void cvt_pair(float f0, float f1,
                                         unsigned int& hi, unsigned int& lo) {
  unsigned int u0 = __float_as_uint(f0), u1 = __float_as_uint(f1);
  hi = __builtin_amdgcn_perm(u1, u0, 0x07060302u);
  float l0 = f0 - __uint_as_float(u0 & 0xFFFF0000u);
  float l1 = f1 - __uint_as_float(u1 & 0xFFFF0000u);
  lo = __builtin_amdgcn_perm(__float_as_uint(l1), __float_as_uint(l0), 0x07060302u);
}

// raw barriers: no vmcnt drain (prefetched global loads ride across);
// lgkm0 variant publishes ds_writes before the barrier.
__device__ __forceinline__ void fence_barrier() {
  asm volatile("" ::: "memory");
  __builtin_amdgcn_s_barrier();
  asm volatile("" ::: "memory");
}
__device__ __forceinline__ void lgkm0_barrier() {
  asm volatile("s_waitcnt lgkmcnt(0)" ::: "memory");
  __builtin_amdgcn_s_barrier();
  asm volatile("" ::: "memory");
}

// ---------------- weight pre-convert/transpose (runs once, tiny) ----------------
__global__ __launch_bounds__(256) void k_prepw(
    const float* __restrict__ Wdes, const float* __restrict__ Wtw,
    const float* __restrict__ Wnum, const float* __restrict__ Wcat,
    const float* __restrict__ Win,  const float* __restrict__ root1,
    const float* __restrict__ rel1, const float* __restrict__ root2,
    const float* __restrict__ rel2, const float* __restrict__ Wcls,
    unsigned short* __restrict__ Wt) {
  int id = blockIdx.x * 256 + threadIdx.x;
  if (id >= WT_SITES) return;
  const float* src; int K, Kpad, dhi, dlo, local;
  if (id < 98304)       { src=Wdes;        K=768; Kpad=768; dhi=OFF_DES_HI;       dlo=OFF_DES_LO;       local=id; }
  else if (id < 196608) { src=Wtw;         K=768; Kpad=768; dhi=OFF_TW_HI;        dlo=OFF_TW_LO;        local=id-98304; }
  else if (id < 200704) { src=Wnum;        K=6;   Kpad=32;  dhi=OFF_NUM_HI;       dlo=OFF_NUM_LO;       local=id-196608; }
  else if (id < 204800) { src=Wcat;        K=11;  Kpad=32;  dhi=OFF_CAT_HI;       dlo=OFF_CAT_LO;       local=id-200704; }
  else if (id < 270336) { src=Win;         K=512; Kpad=512; dhi=OFF_WIN_HI;       dlo=OFF_WIN_LO;       local=id-204800; }
  else if (id < 286720) { src=root1;       K=128; Kpad=128; dhi=OFF_L1_HI;        dlo=OFF_L1_LO;        local=id-270336; }
  else if (id < 303104) { src=rel1;        K=128; Kpad=128; dhi=OFF_L1_HI+16384;  dlo=OFF_L1_LO+16384;  local=id-286720; }
  else if (id < 319488) { src=rel1+16384;  K=128; Kpad=128; dhi=OFF_L1_HI+32768;  dlo=OFF_L1_LO+32768;  local=id-303104; }
  else if (id < 335872) { src=root2;       K=128; Kpad=128; dhi=OFF_L2_HI;        dlo=OFF_L2_LO;        local=id-319488; }
  else if (id < 352256) { src=rel2;        K=128; Kpad=128; dhi=OFF_L2_HI+16384;  dlo=OFF_L2_LO+16384;  local=id-335872; }
  else if (id < 368640) { src=rel2+16384;  K=128; Kpad=128; dhi=OFF_L2_HI+32768;  dlo=OFF_L2_LO+32768;  local=id-352256; }
  else                  { src=Wcls;        K=128; Kpad=128; dhi=OFF_CLS_HI;       dlo=OFF_CLS_LO;       local=id-368640; }
  int col = local / Kpad;
  int k = local - col * Kpad;
  float v = (k < K) ? src[(size_t)k * 128 + col] : 0.f;
  unsigned int u = __float_as_uint(v);
  float lo = v - __uint_as_float(u & 0xFFFF0000u);
  Wt[dhi + col * Kpad + k] = (unsigned short)(u >> 16);
  Wt[dlo + col * Kpad + k] = (unsigned short)(__float_as_uint(lo) >> 16);
}

// ---------------- CSR build ----------------
__global__ __launch_bounds__(256) void k_count(const int* __restrict__ ei,
                                               const int* __restrict__ et,
                                               int* __restrict__ cnt2) {
  int e = blockIdx.x * 256 + threadIdx.x;
  if (e >= EE) return;
  atomicAdd(&cnt2[et[e] * NN + ei[EE + e]], 1);
}

__global__ __launch_bounds__(256) void k_scan1(const int* __restrict__ cnt2,
                                               int* __restrict__ row_ptr,
                                               int* __restrict__ bsum) {
  __shared__ int sums[256];
  int t = threadIdx.x;
  int base = blockIdx.x * 1024 + t * 4;
  int v[4]; int s = 0;
#pragma unroll
  for (int j = 0; j < 4; ++j) {
    int idx = base + j;
    v[j] = (idx < NN) ? (cnt2[idx] + cnt2[NN + idx]) : 0;
    s += v[j];
  }
  sums[t] = s;
  __syncthreads();
  for (int d = 1; d < 256; d <<= 1) {
    int val = (t >= d) ? sums[t - d] : 0;
    __syncthreads();
    sums[t] += val;
    __syncthreads();
  }
  int excl = sums[t] - s;
  if (t == 255) bsum[blockIdx.x] = sums[t];
  int run = excl;
#pragma unroll
  for (int j = 0; j < 4; ++j) {
    int idx = base + j;
    if (idx < NN) row_ptr[idx] = run;
    run += v[j];
  }
}

__global__ __launch_bounds__(128) void k_scan2(int* __restrict__ bsum, int nb) {
  __shared__ int s[128];
  int t = threadIdx.x;
  int v = (t < nb) ? bsum[t] : 0;
  s[t] = v;
  __syncthreads();
  for (int d = 1; d < 128; d <<= 1) {
    int val = (t >= d) ? s[t - d] : 0;
    __syncthreads();
    s[t] += val;
    __syncthreads();
  }
  if (t < nb) bsum[t] = s[t] - v;
}

__global__ __launch_bounds__(256) void k_scan3(int* __restrict__ row_ptr,
                                               const int* __restrict__ bsum) {
  int idx = blockIdx.x * 256 + threadIdx.x;
  if (idx < NN) row_ptr[idx] += bsum[idx >> 10];
  if (idx == NN) row_ptr[NN] = EE;
}

__global__ __launch_bounds__(256) void k_fill(const int* __restrict__ ei,
                                              const int* __restrict__ et,
                                              const int* __restrict__ row_ptr,
                                              int* __restrict__ fillpos,
                                              int* __restrict__ entries) {
  int e = blockIdx.x * 256 + threadIdx.x;
  if (e >= EE) return;
  int src = ei[e];
  int dst = ei[EE + e];
  int r = et[e];
  int pos = atomicAdd(&fillpos[dst], 1);
  entries[row_ptr[dst] + pos] = src | (r << 20);
}

// ---------------- fused projection (MFMA, split-bf16, pipelined, raw barriers) ----
// 64 nodes/block, 4 waves, wave = 16 rows x 128 cols (no duplicated A-loads,
// z is wave-private). 1-deep register prefetch of x rows + W tiles; raw
// s_barrier (no vmcnt drain) so prefetched loads ride across sync points.
__global__ __launch_bounds__(256, 2) void k_proj2(
    const float* __restrict__ x,
    const float* __restrict__ bdes, const float* __restrict__ btw,
    const float* __restrict__ bnum, const float* __restrict__ bcat,
    const float* __restrict__ bin,  const float* __restrict__ pa,
    const unsigned short* __restrict__ Wt, float* __restrict__ h0) {
  __shared__ unsigned short bt_hi[128 * 32], bt_lo[128 * 32];   // 8KB + 8KB
  __shared__ unsigned short z_hi[64 * 128], z_lo[64 * 128];     // 16KB + 16KB

  const int t = threadIdx.x;
  const int node0 = blockIdx.x * 64;
  const int w = t >> 6, lane = t & 63;
  const int li = lane & 15, lg = lane >> 4;

  // B-staging constants (loop-invariant per thread)
  const int cr0 = t >> 2, c0 = t & 3;
  const int cr1 = cr0 + 64;
  const unsigned stb0 = cr0 * 64 + ((c0 ^ ((cr0 >> 1) & 3)) << 4);
  const unsigned stb1 = cr1 * 64 + ((c0 ^ ((cr1 >> 1) & 3)) << 4);

  // one A-row per (wave, li)
  int nodeA = node0 + w * 16 + li;
  int ndA = nodeA < NN ? nodeA : NN - 1;
  const float* xrow = x + (size_t)ndA * XDIM;

#define STORE_BT(SH0, SL0, SH1, SL1)              \
  do {                                            \
    *(uint4*)((char*)bt_hi + stb0) = (SH0);       \
    *(uint4*)((char*)bt_lo + stb0) = (SL0);       \
    *(uint4*)((char*)bt_hi + stb1) = (SH1);       \
    *(uint4*)((char*)bt_lo + stb1) = (SL1);       \
  } while (0)

#define MFMA_A(F, ZACC)                                                          \
  do {                                                                           \
    Frag ah_, al_;                                                               \
    _Pragma("unroll")                                                            \
    for (int q_ = 0; q_ < 4; ++q_)                                               \
      cvt_pair((F)[2 * q_], (F)[2 * q_ + 1], ah_.u[q_], al_.u[q_]);              \
    _Pragma("unroll")                                                            \
    for (int ct_ = 0; ct_ < 8; ++ct_) {                                          \
      int colrow_ = ct_ * 16 + li;                                               \
      int byte_ = colrow_ * 64 + (lg << 4);                                      \
      byte_ ^= ((colrow_ >> 1) & 3) << 4;                                        \
      Frag bh_, bl_;                                                             \
      bh_.v = *(const uint4*)((char*)bt_hi + byte_);                             \
      bl_.v = *(const uint4*)((char*)bt_lo + byte_);                             \
      (ZACC)[ct_] = __builtin_amdgcn_mfma_f32_16x16x32_bf16(ah_.s, bl_.s, (ZACC)[ct_], 0, 0, 0); \
      (ZACC)[ct_] = __builtin_amdgcn_mfma_f32_16x16x32_bf16(al_.s, bh_.s, (ZACC)[ct_], 0, 0, 0); \
      (ZACC)[ct_] = __builtin_amdgcn_mfma_f32_16x16x32_bf16(ah_.s, bh_.s, (ZACC)[ct_], 0, 0, 0); \
    }                                                                            \
  } while (0)

#define MFMA_B(KT)                                                               \
  do {                                                                           \
    Frag ah_, al_;                                                               \
    {                                                                            \
      int row_ = w * 16 + li;                                                    \
      int byte_ = row_ * 256 + (((KT) * 32 + lg * 8) << 1);                      \
      byte_ ^= (row_ & 7) << 4;                                                  \
      ah_.v = *(const uint4*)((char*)z_hi + byte_);                              \
      al_.v = *(const uint4*)((char*)z_lo + byte_);                              \
    }                                                                            \
    _Pragma("unroll")                                                            \
    for (int ct_ = 0; ct_ < 8; ++ct_) {                                          \
      int colrow_ = ct_ * 16 + li;                                               \
      int byte_ = colrow_ * 64 + (lg << 4);                                      \
      byte_ ^= ((colrow_ >> 1) & 3) << 4;                                        \
      Frag bh_, bl_;                                                             \
      bh_.v = *(const uint4*)((char*)bt_hi + byte_);                             \
      bl_.v = *(const uint4*)((char*)bt_lo + byte_);                             \
      hacc[ct_] = __builtin_amdgcn_mfma_f32_16x16x32_bf16(ah_.s, bl_.s, hacc[ct_], 0, 0, 0); \
      hacc[ct_] = __builtin_amdgcn_mfma_f32_16x16x32_bf16(al_.s, bh_.s, hacc[ct_], 0, 0, 0); \
      hacc[ct_] = __builtin_amdgcn_mfma_f32_16x16x32_bf16(ah_.s, bh_.s, hacc[ct_], 0, 0, 0); \
    }                                                                            \
  } while (0)

#define Z_EPI(ZACC, BIASP)                                                       \
  do {                                                                           \
    _Pragma("unroll")                                                            \
    for (int ct_ = 0; ct_ < 8; ++ct_) {                                          \
      int col_ = ct_ * 16 + li;                                                  \
      float bv_ = (BIASP)[col_];                                                 \
      _Pragma("unroll")                                                          \
      for (int r_ = 0; r_ < 4; ++r_) {                                           \
        float v_ = (ZACC)[ct_][r_] + bv_;                                        \
        v_ = v_ >= 0.f ? v_ : 0.01f * v_;                                        \
        int row_ = w * 16 + lg * 4 + r_;                                         \
        int byte_ = row_ * 256 + col_ * 2;                                       \
        byte_ ^= (row_ & 7) << 4;                                                \
        unsigned int u_ = __float_as_uint(v_);                                   \
        *(unsigned short*)((char*)z_hi + byte_) = (unsigned short)(u_ >> 16);    \
        float lo_ = v_ - __uint_as_float(u_ & 0xFFFF0000u);                      \
        *(unsigned short*)((char*)z_lo + byte_) = (unsigned short)(__float_as_uint(lo_) >> 16); \
      }                                                                          \
    }                                                                            \
  } while (0)

// phase B: hacc += z @ Win[SLICE*128 .. +127], 4 K-tiles, fully unrolled,
// 1-deep prefetch of the next Win tile.
#define PHASE_B(SLICE)                                                           \
  do {                                                                           \
    const unsigned short* qh0_ = Wt + OFF_WIN_HI + cr0 * 512 + (SLICE) * 128 + c0 * 8; \
    const unsigned short* ql0_ = Wt + OFF_WIN_LO + cr0 * 512 + (SLICE) * 128 + c0 * 8; \
    const unsigned short* qh1_ = Wt + OFF_WIN_HI + cr1 * 512 + (SLICE) * 128 + c0 * 8; \
    const unsigned short* ql1_ = Wt + OFF_WIN_LO + cr1 * 512 + (SLICE) * 128 + c0 * 8; \
    uint4 wA0_ = *(const uint4*)(qh0_), wA1_ = *(const uint4*)(ql0_);            \
    uint4 wA2_ = *(const uint4*)(qh1_), wA3_ = *(const uint4*)(ql1_);            \
    uint4 wB0_, wB1_, wB2_, wB3_;                                                \
    STORE_BT(wA0_, wA1_, wA2_, wA3_);                                            \
    lgkm0_barrier();                                                             \
    wB0_ = *(const uint4*)(qh0_ + 32); wB1_ = *(const uint4*)(ql0_ + 32);        \
    wB2_ = *(const uint4*)(qh1_ + 32); wB3_ = *(const uint4*)(ql1_ + 32);        \
    MFMA_B(0);                                                                   \
    fence_barrier();                                                             \
    STORE_BT(wB0_, wB1_, wB2_, wB3_);                                            \
    lgkm0_barrier();                                                             \
    wA0_ = *(const uint4*)(qh0_ + 64); wA1_ = *(const uint4*)(ql0_ + 64);        \
    wA2_ = *(const uint4*)(qh1_ + 64); wA3_ = *(const uint4*)(ql1_ + 64);        \
    MFMA_B(1);                                                                   \
    fence_barrier();                                                             \
    STORE_BT(wA0_, wA1_, wA2_, wA3_);                                            \
    lgkm0_barrier();                                                             \
    wB0_ = *(const uint4*)(qh0_ + 96); wB1_ = *(const uint4*)(ql0_ + 96);        \
    wB2_ = *(const uint4*)(qh1_ + 96); wB3_ = *(const uint4*)(ql1_ + 96);        \
    MFMA_B(2);                                                                   \
    fence_barrier();                                                             \
    STORE_BT(wB0_, wB1_, wB2_, wB3_);                                            \
    lgkm0_barrier();                                                             \
    MFMA_B(3);                                                                   \
    fence_barrier();                                                             \
  } while (0)

  f32x4 hacc[8];
#pragma unroll
  for (int b = 0; b < 8; ++b) hacc[b] = (f32x4)0.f;

  // ---- big segments: des (s=0), tweet (s=1); K=768 = 24 K-tiles, pipelined ----
#pragma unroll
  for (int s = 0; s < 2; ++s) {
    const int off = (s == 0) ? 785 : 6;
    const unsigned short* wh = Wt + (s == 0 ? OFF_DES_HI : OFF_TW_HI);
    const unsigned short* wl = Wt + (s == 0 ? OFF_DES_LO : OFF_TW_LO);
    const float* bias = (s == 0) ? bdes : btw;

    const float* xr = xrow + off + lg * 8;
    const unsigned short* ph0 = wh + cr0 * 768 + c0 * 8;
    const unsigned short* pl0 = wl + cr0 * 768 + c0 * 8;
    const unsigned short* ph1 = wh + cr1 * 768 + c0 * 8;
    const unsigned short* pl1 = wl + cr1 * 768 + c0 * 8;

    f32x4 zacc[8];
#pragma unroll
    for (int b = 0; b < 8; ++b) zacc[b] = (f32x4)0.f;

    uint4 bA0, bA1, bA2, bA3, bB0, bB1, bB2, bB3;
    float fA[8], fB[8];

    // prologue: issue kt=0
    bA0 = *(const uint4*)(ph0); bA1 = *(const uint4*)(pl0);
    bA2 = *(const uint4*)(ph1); bA3 = *(const uint4*)(pl1);
#pragma unroll
    for (int j = 0; j < 8; ++j) fA[j] = xr[j];

    for (int kt = 0; kt < 24; kt += 2) {
      // even K-tile: consume A-regs, prefetch kt+1 into B-regs
      STORE_BT(bA0, bA1, bA2, bA3);
      lgkm0_barrier();
      {
        const int ko = (kt + 1) * 32;
        bB0 = *(const uint4*)(ph0 + ko); bB1 = *(const uint4*)(pl0 + ko);
        bB2 = *(const uint4*)(ph1 + ko); bB3 = *(const uint4*)(pl1 + ko);
#pragma unroll
        for (int j = 0; j < 8; ++j) fB[j] = xr[ko + j];
      }
      MFMA_A(fA, zacc);
      fence_barrier();
      // odd K-tile: consume B-regs, prefetch kt+2 into A-regs
      STORE_BT(bB0, bB1, bB2, bB3);
      lgkm0_barrier();
      if (kt + 2 < 24) {
        const int ko = (kt + 2) * 32;
        bA0 = *(const uint4*)(ph0 + ko); bA1 = *(const uint4*)(pl0 + ko);
        bA2 = *(const uint4*)(ph1 + ko); bA3 = *(const uint4*)(pl1 + ko);
#pragma unroll
        for (int j = 0; j < 8; ++j) fA[j] = xr[ko + j];
      }
      MFMA_A(fB, zacc);
      fence_barrier();
    }
    Z_EPI(zacc, bias);   // z is wave-private: no barrier needed for z itself
    PHASE_B(s);
  }

  // ---- small segments: num (K=6), cat (K=11); single padded K-tile each ----
#pragma unroll
  for (int u = 0; u < 2; ++u) {
    const int offu = (u == 0) ? 0 : 774;
    const int Ksu = (u == 0) ? 6 : 11;
    const unsigned short* wh = Wt + (u == 0 ? OFF_NUM_HI : OFF_CAT_HI);
    const unsigned short* wl = Wt + (u == 0 ? OFF_NUM_LO : OFF_CAT_LO);
    const float* biasu = (u == 0) ? bnum : bcat;
    const float* xr = xrow + offu + lg * 8;

    uint4 s0 = *(const uint4*)(wh + cr0 * 32 + c0 * 8);
    uint4 s1 = *(const uint4*)(wl + cr0 * 32 + c0 * 8);
    uint4 s2 = *(const uint4*)(wh + cr1 * 32 + c0 * 8);
    uint4 s3 = *(const uint4*)(wl + cr1 * 32 + c0 * 8);
    float f[8];
#pragma unroll
    for (int j = 0; j < 8; ++j) f[j] = xr[j];
#pragma unroll
    for (int j = 0; j < 8; ++j)
      if (lg * 8 + j >= Ksu) f[j] = 0.f;

    f32x4 zacc[8];
#pragma unroll
    for (int b = 0; b < 8; ++b) zacc[b] = (f32x4)0.f;

    STORE_BT(s0, s1, s2, s3);
    lgkm0_barrier();
    MFMA_A(f, zacc);
    fence_barrier();
    Z_EPI(zacc, biasu);
    PHASE_B(u + 2);
  }

  // epilogue: + b_in, PReLU, store
#pragma unroll
  for (int ct = 0; ct < 8; ++ct) {
    int col = ct * 16 + li;
    float bi = bin[col];
    float p = pa[col];
#pragma unroll
    for (int r = 0; r < 4; ++r) {
      int node = node0 + w * 16 + lg * 4 + r;
      if (node < NN) {
        float v = hacc[ct][r] + bi;
        v = v >= 0.f ? v : p * v;
        h0[(size_t)node * HD + col] = v;
      }
    }
  }

#undef STORE_BT
#undef MFMA_A
#undef MFMA_B
#undef Z_EPI
#undef PHASE_B
}

// ---------------- layer GEMM: hin @ [root|rel0|rel1] (MFMA split-bf16) ----------------
// 64 rows/block, 4 waves: wave = 64 rows x 96 cols (of 384).
__global__ __launch_bounds__(256, 2) void k_rgemm(
    const float* __restrict__ hin, const unsigned short* __restrict__ wl_hi,
    const unsigned short* __restrict__ wl_lo, const float* __restrict__ bias,
    float* __restrict__ base, float* __restrict__ mh) {
  __shared__ unsigned short bt_hi[384 * 32], bt_lo[384 * 32];  // 24KB + 24KB

  const int t = threadIdx.x;
  const int node0 = blockIdx.x * 64;
  const int w = t >> 6, lane = t & 63;
  const int li = lane & 15, lg = lane >> 4;

  f32x4 acc[4][6];
#pragma unroll
  for (int a = 0; a < 4; ++a)
#pragma unroll
    for (int b = 0; b < 6; ++b) acc[a][b] = (f32x4)0.f;

  for (int kt = 0; kt < 4; ++kt) {
    // stage B tile [384][32] hi/lo
    uint4 sh[6], sl[6]; int scr[6], scc[6];
#pragma unroll
    for (int j = 0; j < 6; ++j) {
      int cid = t + j * 256;
      int cr = cid >> 2, c = cid & 3;
      scr[j] = cr; scc[j] = c;
      sh[j] = *(const uint4*)(wl_hi + cr * 128 + kt * 32 + c * 8);
      sl[j] = *(const uint4*)(wl_lo + cr * 128 + kt * 32 + c * 8);
    }
    __syncthreads();
#pragma unroll
    for (int j = 0; j < 6; ++j) {
      int byte = scr[j] * 64 + ((scc[j] ^ ((scr[j] >> 1) & 3)) << 4);
      *(uint4*)((char*)bt_hi + byte) = sh[j];
      *(uint4*)((char*)bt_lo + byte) = sl[j];
    }
    __syncthreads();
    // A fragments (after barrier to keep reg peak low)
    Frag ah[4], al[4];
#pragma unroll
    for (int sub = 0; sub < 4; ++sub) {
      int node = node0 + sub * 16 + li;
      int nd = node < NN ? node : NN - 1;
      const float4* hr = (const float4*)(hin + (size_t)nd * HD + kt * 32 + lg * 8);
      float4 fa = hr[0], fb = hr[1];
      cvt_pair(fa.x, fa.y, ah[sub].u[0], al[sub].u[0]);
      cvt_pair(fa.z, fa.w, ah[sub].u[1], al[sub].u[1]);
      cvt_pair(fb.x, fb.y, ah[sub].u[2], al[sub].u[2]);
      cvt_pair(fb.z, fb.w, ah[sub].u[3], al[sub].u[3]);
    }
#pragma unroll
    for (int ct = 0; ct < 6; ++ct) {
      int colrow = w * 96 + ct * 16 + li;
      int byte = colrow * 64 + (lg << 4);
      byte ^= ((colrow >> 1) & 3) << 4;
      Frag bh, bl;
      bh.v = *(const uint4*)((char*)bt_hi + byte);
      bl.v = *(const uint4*)((char*)bt_lo + byte);
#pragma unroll
      for (int sub = 0; sub < 4; ++sub) {
        acc[sub][ct] = __builtin_amdgcn_mfma_f32_16x16x32_bf16(ah[sub].s, bl.s, acc[sub][ct], 0, 0, 0);
        acc[sub][ct] = __builtin_amdgcn_mfma_f32_16x16x32_bf16(al[sub].s, bh.s, acc[sub][ct], 0, 0, 0);
        acc[sub][ct] = __builtin_amdgcn_mfma_f32_16x16x32_bf16(ah[sub].s, bh.s, acc[sub][ct], 0, 0, 0);
      }
    }
  }
  // epilogue
#pragma unroll
  for (int ct = 0; ct < 6; ++ct) {
    int gcol = w * 96 + ct * 16 + li;
    float bv = 0.f;
    float* dp;
    int lc;
    if (gcol < 128) { bv = bias[gcol]; dp = base; lc = gcol; }
    else if (gcol < 256) { dp = mh; lc = gcol - 128; }
    else { dp = mh + (size_t)NN * HD; lc = gcol - 256; }
#pragma unroll
    for (int sub = 0; sub < 4; ++sub) {
#pragma unroll
      for (int r = 0; r < 4; ++r) {
        int node = node0 + sub * 16 + lg * 4 + r;
        if (node < NN) dp[(size_t)node * HD + lc] = acc[sub][ct][r] + bv;
      }
    }
  }
}

// ---------------- aggregation ----------------
__global__ __launch_bounds__(256) void k_aggregate(
    float* __restrict__ io, const float* __restrict__ mh,
    const int* __restrict__ row_ptr, const int* __restrict__ cnt2,
    const int* __restrict__ entries) {
  int i = blockIdx.x * 4 + (threadIdx.x >> 6);
  int l = threadIdx.x & 63;
  if (i >= NN) return;
  int rs = row_ptr[i], re = row_ptr[i + 1];
  int c0 = cnt2[i], c1 = cnt2[NN + i];
  float inv0 = 1.f / (float)(c0 > 0 ? c0 : 1);
  float inv1 = 1.f / (float)(c1 > 0 ? c1 : 1);
  float a0 = 0, a1 = 0, b0 = 0, b1 = 0;
  int e = rs;
  for (; e + 1 < re; e += 2) {
    int ent0 = entries[e], ent1 = entries[e + 1];
    const float* r0 = mh + (((size_t)(ent0 >> 20)) * NN + (ent0 & 0xFFFFF)) * HD;
    const float* r1 = mh + (((size_t)(ent1 >> 20)) * NN + (ent1 & 0xFFFFF)) * HD;
    float v00 = r0[l], v01 = r0[l + 64];
    float v10 = r1[l], v11 = r1[l + 64];
    if (ent0 >> 20) { b0 += v00; b1 += v01; } else { a0 += v00; a1 += v01; }
    if (ent1 >> 20) { b0 += v10; b1 += v11; } else { a0 += v10; a1 += v11; }
  }
  if (e < re) {
    int ent = entries[e];
    const float* r0 = mh + (((size_t)(ent >> 20)) * NN + (ent & 0xFFFFF)) * HD;
    float v0 = r0[l], v1 = r0[l + 64];
    if (ent >> 20) { b0 += v0; b1 += v1; } else { a0 += v0; a1 += v1; }
  }
  io[(size_t)i * HD + l] += a0 * inv0 + b0 * inv1;
  io[(size_t)i * HD + l + 64] += a1 * inv0 + b1 * inv1;
}

// ---------------- final linear (MFMA, in-place) ----------------
// 64 rows/block, 4 waves in 2x2: wave = 32 rows x 64 cols.
__global__ __launch_bounds__(256, 2) void k_cls2(
    float* __restrict__ io, const unsigned short* __restrict__ Wt,
    const float* __restrict__ b) {
  __shared__ unsigned short bt_hi[128 * 32], bt_lo[128 * 32];  // 8KB + 8KB

  const int t = threadIdx.x;
  const int node0 = blockIdx.x * 64;
  const int w = t >> 6, lane = t & 63;
  const int li = lane & 15, lg = lane >> 4;
  const int wr = w >> 1, wc = w & 1;

  f32x4 acc[2][4];
#pragma unroll
  for (int a = 0; a < 2; ++a)
#pragma unroll
    for (int bq = 0; bq < 4; ++bq) acc[a][bq] = (f32x4)0.f;

  for (int kt = 0; kt < 4; ++kt) {
    uint4 sh[2], sl[2]; int scr[2], scc[2];
#pragma unroll
    for (int j = 0; j < 2; ++j) {
      int cid = t + j * 256;
      int cr = cid >> 2, c = cid & 3;
      scr[j] = cr; scc[j] = c;
      sh[j] = *(const uint4*)(Wt + OFF_CLS_HI + cr * 128 + kt * 32 + c * 8);
      sl[j] = *(const uint4*)(Wt + OFF_CLS_LO + cr * 128 + kt * 32 + c * 8);
    }
    __syncthreads();
#pragma unroll
    for (int j = 0; j < 2; ++j) {
      int byte = scr[j] * 64 + ((scc[j] ^ ((scr[j] >> 1) & 3)) << 4);
      *(uint4*)((char*)bt_hi + byte) = sh[j];
      *(uint4*)((char*)bt_lo + byte) = sl[j];
    }
    __syncthreads();
    Frag ah[2], al[2];
#pragma unroll
    for (int sub = 0; sub < 2; ++sub) {
      int node = node0 + wr * 32 + sub * 16 + li;
      int nd = node < NN ? node : NN - 1;
      const float4* hr = (const float4*)(io + (size_t)nd * HD + kt * 32 + lg * 8);
      float4 fa = hr[0], fb = hr[1];
      cvt_pair(fa.x, fa.y, ah[sub].u[0], al[sub].u[0]);
      cvt_pair(fa.z, fa.w, ah[sub].u[1], al[sub].u[1]);
      cvt_pair(fb.x, fb.y, ah[sub].u[2], al[sub].u[2]);
      cvt_pair(fb.z, fb.w, ah[sub].u[3], al[sub].u[3]);
    }
#pragma unroll
    for (int ct = 0; ct < 4; ++ct) {
      int colrow = wc * 64 + ct * 16 + li;
      int byte = colrow * 64 + (lg << 4);
      byte ^= ((colrow >> 1) & 3) << 4;
      Frag bh, bl;
      bh.v = *(const uint4*)((char*)bt_hi + byte);
      bl.v = *(const uint4*)((char*)bt_lo + byte);
#pragma unroll
      for (int sub = 0; sub < 2; ++sub) {
        acc[sub][ct] = __builtin_amdgcn_mfma_f32_16x16x32_bf16(ah[sub].s, bl.s, acc[sub][ct], 0, 0, 0);
        acc[sub][ct] = __builtin_amdgcn_mfma_f32_16x16x32_bf16(al[sub].s, bh.s, acc[sub][ct], 0, 0, 0);
        acc[sub][ct] = __builtin_amdgcn_mfma_f32_16x16x32_bf16(ah[sub].s, bh.s, acc[sub][ct], 0, 0, 0);
      }
    }
  }
  __syncthreads();  // all A-reads of this block's rows done before in-place writes
#pragma unroll
  for (int ct = 0; ct < 4; ++ct) {
    int col = wc * 64 + ct * 16 + li;
    float bv = b[col];
#pragma unroll
    for (int sub = 0; sub < 2; ++sub) {
#pragma unroll
      for (int r = 0; r < 4; ++r) {
        int node = node0 + wr * 32 + sub * 16 + lg * 4 + r;
        if (node < NN) io[(size_t)node * HD + col] = acc[sub][ct][r] + bv;
      }
    }
  }
}

extern "C" void kernel_launch(void* const* d_in, const int* in_sizes, int n_in,
                              void* d_out, int out_size, void* d_ws, size_t ws_size,
                              hipStream_t stream) {
  const float* x    = (const float*)d_in[0];
  const int* ei     = (const int*)d_in[1];
  const int* et     = (const int*)d_in[2];
  const float* Wdes = (const float*)d_in[3];
  const float* bdes = (const float*)d_in[4];
  const float* Wtw  = (const float*)d_in[5];
  const float* btw  = (const float*)d_in[6];
  const float* Wnum = (const float*)d_in[7];
  const float* bnum = (const float*)d_in[8];
  const float* Wcat = (const float*)d_in[9];
  const float* bcat = (const float*)d_in[10];
  const float* Win  = (const float*)d_in[11];
  const float* bin  = (const float*)d_in[12];
  const float* pa   = (const float*)d_in[13];
  const float* root1 = (const float*)d_in[14];
  const float* rel1  = (const float*)d_in[15];
  const float* bias1 = (const float*)d_in[16];
  const float* root2 = (const float*)d_in[17];
  const float* rel2  = (const float*)d_in[18];
  const float* bias2 = (const float*)d_in[19];
  const float* Wcls  = (const float*)d_in[20];
  const float* bcls  = (const float*)d_in[21];
  float* out = (float*)d_out;

  char* p = (char*)d_ws;
  float* mh = (float*)p;      p += (size_t)2 * NN * HD * 4;   // 102.4 MB
  float* hB = (float*)p;      p += (size_t)NN * HD * 4;       // 51.2 MB
  int* row_ptr = (int*)p;     p += ((size_t)NN + 4) * 4;
  int* cnt2 = (int*)p;        p += (size_t)2 * NN * 4;
  int* fillpos = (int*)p;     p += (size_t)NN * 4;
  int* entries = (int*)p;     p += (size_t)EE * 4;
  int* bsum = (int*)p;        p += 512;
  unsigned short* Wt = (unsigned short*)p;  p += (size_t)WT_SITES * 2 * 2;

  // weight pre-convert (independent of everything else)
  k_prepw<<<(WT_SITES + 255) / 256, 256, 0, stream>>>(
      Wdes, Wtw, Wnum, Wcat, Win, root1, rel1, root2, rel2, Wcls, Wt);

  // CSR build
  hipMemsetAsync(cnt2, 0, (size_t)3 * NN * 4, stream);  // cnt2 + fillpos
  k_count<<<EE / 256, 256, 0, stream>>>(ei, et, cnt2);
  int nb = (NN + 1023) / 1024;
  k_scan1<<<nb, 256, 0, stream>>>(cnt2, row_ptr, bsum);
  k_scan2<<<1, 128, 0, stream>>>(bsum, nb);
  k_scan3<<<(NN + 1 + 255) / 256, 256, 0, stream>>>(row_ptr, bsum);
  k_fill<<<EE / 256, 256, 0, stream>>>(ei, et, row_ptr, fillpos, entries);

  const int nblk = (NN + 63) / 64;  // 1563
  // h0 -> d_out
  k_proj2<<<nblk, 256, 0, stream>>>(x, bdes, btw, bnum, bcat, bin, pa, Wt, out);
  // layer 1
  k_rgemm<<<nblk, 256, 0, stream>>>(out, Wt + OFF_L1_HI, Wt + OFF_L1_LO, bias1, hB, mh);
  k_aggregate<<<NN / 4, 256, 0, stream>>>(hB, mh, row_ptr, cnt2, entries);
  // layer 2
  k_rgemm<<<nblk, 256, 0, stream>>>(hB, Wt + OFF_L2_HI, Wt + OFF_L2_LO, bias2, out, mh);
  k_aggregate<<<NN / 4, 256, 0, stream>>>(out, mh, row_ptr, cnt2, entries);
  // classifier (MFMA, in-place)
  k_cls2<<<nblk, 256, 0, stream>>>(out, Wt, bcls);
}

// Round 2
// 1062.689 us; speedup vs baseline: 1.6619x; 1.2110x over previous
//
#include <hip/hip_runtime.h>
#include <cstdint>
#include <cstddef>

#define NN 100000
#define EE 1600000
#define XDIM 1553
#define HD 128

typedef __attribute__((ext_vector_type(8))) short short8;
typedef __attribute__((ext_vector_type(4))) float f32x4;

union Frag { unsigned int u[4]; short8 s; uint4 v; };

// weight area offsets (ushort units); hi/lo are separate regions
#define OFF_DES_HI 0
#define OFF_DES_LO 98304
#define OFF_TW_HI  196608
#define OFF_TW_LO  294912
#define OFF_NUM_HI 393216
#define OFF_NUM_LO 397312
#define OFF_CAT_HI 401408
#define OFF_CAT_LO 405504
#define OFF_WIN_HI 409600
#define OFF_WIN_LO 475136
#define OFF_L1_HI  540672
#define OFF_L1_LO  589824
#define OFF_L2_HI  638976
#define OFF_L2_LO  688128
#define OFF_CLS_HI 737280
#define OFF_CLS_LO 753664
#define WT_SITES   385024   // (col,k) sites; each writes hi+lo

// hi = trunc-bf16(f), lo = trunc-bf16(f - hi). Packed: 2 elems -> 1 u32 via v_perm.
__device__ __forceinline__ void cvt_pair(float f0, float f1,
                                         unsigned int& hi, unsigned int& lo) {
  unsigned int u0 = __float_as_uint(f0), u1 = __float_as_uint(f1);
  hi = __builtin_amdgcn_perm(u1, u0, 0x07060302u);
  float l0 = f0 - __uint_as_float(u0 & 0xFFFF0000u);
  float l1 = f1 - __uint_as_float(u1 & 0xFFFF0000u);
  lo = __builtin_amdgcn_perm(__float_as_uint(l1), __float_as_uint(l0), 0x07060302u);
}

// raw barriers: no vmcnt drain (prefetched global loads ride across);
// lgkm0 variant publishes ds_writes before the barrier.
__device__ __forceinline__ void fence_barrier() {
  asm volatile("" ::: "memory");
  __builtin_amdgcn_s_barrier();
  asm volatile("" ::: "memory");
}
__device__ __forceinline__ void lgkm0_barrier() {
  asm volatile("s_waitcnt lgkmcnt(0)" ::: "memory");
  __builtin_amdgcn_s_barrier();
  asm volatile("" ::: "memory");
}

// ---------------- weight pre-convert/transpose (runs once, tiny) ----------------
__global__ __launch_bounds__(256) void k_prepw(
    const float* __restrict__ Wdes, const float* __restrict__ Wtw,
    const float* __restrict__ Wnum, const float* __restrict__ Wcat,
    const float* __restrict__ Win,  const float* __restrict__ root1,
    const float* __restrict__ rel1, const float* __restrict__ root2,
    const float* __restrict__ rel2, const float* __restrict__ Wcls,
    unsigned short* __restrict__ Wt) {
  int id = blockIdx.x * 256 + threadIdx.x;
  if (id >= WT_SITES) return;
  const float* src; int K, Kpad, dhi, dlo, local;
  if (id < 98304)       { src=Wdes;        K=768; Kpad=768; dhi=OFF_DES_HI;       dlo=OFF_DES_LO;       local=id; }
  else if (id < 196608) { src=Wtw;         K=768; Kpad=768; dhi=OFF_TW_HI;        dlo=OFF_TW_LO;        local=id-98304; }
  else if (id < 200704) { src=Wnum;        K=6;   Kpad=32;  dhi=OFF_NUM_HI;       dlo=OFF_NUM_LO;       local=id-196608; }
  else if (id < 204800) { src=Wcat;        K=11;  Kpad=32;  dhi=OFF_CAT_HI;       dlo=OFF_CAT_LO;       local=id-200704; }
  else if (id < 270336) { src=Win;         K=512; Kpad=512; dhi=OFF_WIN_HI;       dlo=OFF_WIN_LO;       local=id-204800; }
  else if (id < 286720) { src=root1;       K=128; Kpad=128; dhi=OFF_L1_HI;        dlo=OFF_L1_LO;        local=id-270336; }
  else if (id < 303104) { src=rel1;        K=128; Kpad=128; dhi=OFF_L1_HI+16384;  dlo=OFF_L1_LO+16384;  local=id-286720; }
  else if (id < 319488) { src=rel1+16384;  K=128; Kpad=128; dhi=OFF_L1_HI+32768;  dlo=OFF_L1_LO+32768;  local=id-303104; }
  else if (id < 335872) { src=root2;       K=128; Kpad=128; dhi=OFF_L2_HI;        dlo=OFF_L2_LO;        local=id-319488; }
  else if (id < 352256) { src=rel2;        K=128; Kpad=128; dhi=OFF_L2_HI+16384;  dlo=OFF_L2_LO+16384;  local=id-335872; }
  else if (id < 368640) { src=rel2+16384;  K=128; Kpad=128; dhi=OFF_L2_HI+32768;  dlo=OFF_L2_LO+32768;  local=id-352256; }
  else                  { src=Wcls;        K=128; Kpad=128; dhi=OFF_CLS_HI;       dlo=OFF_CLS_LO;       local=id-368640; }
  int col = local / Kpad;
  int k = local - col * Kpad;
  float v = (k < K) ? src[(size_t)k * 128 + col] : 0.f;
  unsigned int u = __float_as_uint(v);
  float lo = v - __uint_as_float(u & 0xFFFF0000u);
  Wt[dhi + col * Kpad + k] = (unsigned short)(u >> 16);
  Wt[dlo + col * Kpad + k] = (unsigned short)(__float_as_uint(lo) >> 16);
}

// ---------------- CSR build ----------------
__global__ __launch_bounds__(256) void k_count(const int* __restrict__ ei,
                                               const int* __restrict__ et,
                                               int* __restrict__ cnt2) {
  int e = blockIdx.x * 256 + threadIdx.x;
  if (e >= EE) return;
  atomicAdd(&cnt2[et[e] * NN + ei[EE + e]], 1);
}

__global__ __launch_bounds__(256) void k_scan1(const int* __restrict__ cnt2,
                                               int* __restrict__ row_ptr,
                                               int* __restrict__ bsum) {
  __shared__ int sums[256];
  int t = threadIdx.x;
  int base = blockIdx.x * 1024 + t * 4;
  int v[4]; int s = 0;
#pragma unroll
  for (int j = 0; j < 4; ++j) {
    int idx = base + j;
    v[j] = (idx < NN) ? (cnt2[idx] + cnt2[NN + idx]) : 0;
    s += v[j];
  }
  sums[t] = s;
  __syncthreads();
  for (int d = 1; d < 256; d <<= 1) {
    int val = (t >= d) ? sums[t - d] : 0;
    __syncthreads();
    sums[t] += val;
    __syncthreads();
  }
  int excl = sums[t] - s;
  if (t == 255) bsum[blockIdx.x] = sums[t];
  int run = excl;
#pragma unroll
  for (int j = 0; j < 4; ++j) {
    int idx = base + j;
    if (idx < NN) row_ptr[idx] = run;
    run += v[j];
  }
}

__global__ __launch_bounds__(128) void k_scan2(int* __restrict__ bsum, int nb) {
  __shared__ int s[128];
  int t = threadIdx.x;
  int v = (t < nb) ? bsum[t] : 0;
  s[t] = v;
  __syncthreads();
  for (int d = 1; d < 128; d <<= 1) {
    int val = (t >= d) ? s[t - d] : 0;
    __syncthreads();
    s[t] += val;
    __syncthreads();
  }
  if (t < nb) bsum[t] = s[t] - v;
}

__global__ __launch_bounds__(256) void k_scan3(int* __restrict__ row_ptr,
                                               const int* __restrict__ bsum) {
  int idx = blockIdx.x * 256 + threadIdx.x;
  if (idx < NN) row_ptr[idx] += bsum[idx >> 10];
  if (idx == NN) row_ptr[NN] = EE;
}

__global__ __launch_bounds__(256) void k_fill(const int* __restrict__ ei,
                                              const int* __restrict__ et,
                                              const int* __restrict__ row_ptr,
                                              int* __restrict__ fillpos,
                                              int* __restrict__ entries) {
  int e = blockIdx.x * 256 + threadIdx.x;
  if (e >= EE) return;
  int src = ei[e];
  int dst = ei[EE + e];
  int r = et[e];
  int pos = atomicAdd(&fillpos[dst], 1);
  entries[row_ptr[dst] + pos] = src | (r << 20);
}

// ---------------- fused projection (MFMA, split-bf16, pipelined, raw barriers) ----
// 128 nodes/block, 4 waves, wave = 32 rows x 128 cols. Same B-tile LDS traffic
// and barrier count now serve 2x rows. 1-deep register prefetch of x rows + W
// tiles; raw s_barrier (no vmcnt drain) so prefetched loads ride across syncs.
__global__ __launch_bounds__(256, 2) void k_proj2(
    const float* __restrict__ x,
    const float* __restrict__ bdes, const float* __restrict__ btw,
    const float* __restrict__ bnum, const float* __restrict__ bcat,
    const float* __restrict__ bin,  const float* __restrict__ pa,
    const unsigned short* __restrict__ Wt, float* __restrict__ h0) {
  __shared__ unsigned short bt_hi[128 * 32], bt_lo[128 * 32];   // 8KB + 8KB
  __shared__ unsigned short z_hi[128 * 128], z_lo[128 * 128];   // 32KB + 32KB

  const int t = threadIdx.x;
  const int node0 = blockIdx.x * 128;
  const int w = t >> 6, lane = t & 63;
  const int li = lane & 15, lg = lane >> 4;

  // B-staging constants (loop-invariant per thread)
  const int cr0 = t >> 2, c0 = t & 3;
  const int cr1 = cr0 + 64;
  const unsigned stb0 = cr0 * 64 + ((c0 ^ ((cr0 >> 1) & 3)) << 4);
  const unsigned stb1 = cr1 * 64 + ((c0 ^ ((cr1 >> 1) & 3)) << 4);

  // two A-rows per (wave, li): sub0 = w*32+li, sub1 = +16
  const int rowA0 = w * 32 + li;
  const int rowA1 = rowA0 + 16;
  int nodeA0 = node0 + rowA0; int nd0 = nodeA0 < NN ? nodeA0 : NN - 1;
  int nodeA1 = node0 + rowA1; int nd1 = nodeA1 < NN ? nodeA1 : NN - 1;
  const float* xrow0 = x + (size_t)nd0 * XDIM;
  const float* xrow1 = x + (size_t)nd1 * XDIM;

#define STORE_BT(SH0, SL0, SH1, SL1)              \
  do {                                            \
    *(uint4*)((char*)bt_hi + stb0) = (SH0);       \
    *(uint4*)((char*)bt_lo + stb0) = (SL0);       \
    *(uint4*)((char*)bt_hi + stb1) = (SH1);       \
    *(uint4*)((char*)bt_lo + stb1) = (SL1);       \
  } while (0)

#define MFMA_A(F0, F1, ZACC)                                                     \
  do {                                                                           \
    Frag a0h_, a0l_, a1h_, a1l_;                                                 \
    _Pragma("unroll")                                                            \
    for (int q_ = 0; q_ < 4; ++q_) {                                             \
      cvt_pair((F0)[2 * q_], (F0)[2 * q_ + 1], a0h_.u[q_], a0l_.u[q_]);          \
      cvt_pair((F1)[2 * q_], (F1)[2 * q_ + 1], a1h_.u[q_], a1l_.u[q_]);          \
    }                                                                            \
    _Pragma("unroll")                                                            \
    for (int ct_ = 0; ct_ < 8; ++ct_) {                                          \
      int colrow_ = ct_ * 16 + li;                                               \
      int byte_ = colrow_ * 64 + (lg << 4);                                      \
      byte_ ^= ((colrow_ >> 1) & 3) << 4;                                        \
      Frag bh_, bl_;                                                             \
      bh_.v = *(const uint4*)((char*)bt_hi + byte_);                             \
      bl_.v = *(const uint4*)((char*)bt_lo + byte_);                             \
      (ZACC)[0][ct_] = __builtin_amdgcn_mfma_f32_16x16x32_bf16(a0h_.s, bl_.s, (ZACC)[0][ct_], 0, 0, 0); \
      (ZACC)[0][ct_] = __builtin_amdgcn_mfma_f32_16x16x32_bf16(a0l_.s, bh_.s, (ZACC)[0][ct_], 0, 0, 0); \
      (ZACC)[0][ct_] = __builtin_amdgcn_mfma_f32_16x16x32_bf16(a0h_.s, bh_.s, (ZACC)[0][ct_], 0, 0, 0); \
      (ZACC)[1][ct_] = __builtin_amdgcn_mfma_f32_16x16x32_bf16(a1h_.s, bl_.s, (ZACC)[1][ct_], 0, 0, 0); \
      (ZACC)[1][ct_] = __builtin_amdgcn_mfma_f32_16x16x32_bf16(a1l_.s, bh_.s, (ZACC)[1][ct_], 0, 0, 0); \
      (ZACC)[1][ct_] = __builtin_amdgcn_mfma_f32_16x16x32_bf16(a1h_.s, bh_.s, (ZACC)[1][ct_], 0, 0, 0); \
    }                                                                            \
  } while (0)

#define MFMA_B(KT)                                                               \
  do {                                                                           \
    Frag a0h_, a0l_, a1h_, a1l_;                                                 \
    {                                                                            \
      int byte0_ = rowA0 * 256 + (((KT) * 32 + lg * 8) << 1);                    \
      byte0_ ^= (rowA0 & 7) << 4;                                                \
      a0h_.v = *(const uint4*)((char*)z_hi + byte0_);                            \
      a0l_.v = *(const uint4*)((char*)z_lo + byte0_);                            \
      int byte1_ = rowA1 * 256 + (((KT) * 32 + lg * 8) << 1);                    \
      byte1_ ^= (rowA1 & 7) << 4;                                                \
      a1h_.v = *(const uint4*)((char*)z_hi + byte1_);                            \
      a1l_.v = *(const uint4*)((char*)z_lo + byte1_);                            \
    }                                                                            \
    _Pragma("unroll")                                                            \
    for (int ct_ = 0; ct_ < 8; ++ct_) {                                          \
      int colrow_ = ct_ * 16 + li;                                               \
      int byte_ = colrow_ * 64 + (lg << 4);                                      \
      byte_ ^= ((colrow_ >> 1) & 3) << 4;                                        \
      Frag bh_, bl_;                                                             \
      bh_.v = *(const uint4*)((char*)bt_hi + byte_);                             \
      bl_.v = *(const uint4*)((char*)bt_lo + byte_);                             \
      hacc[0][ct_] = __builtin_amdgcn_mfma_f32_16x16x32_bf16(a0h_.s, bl_.s, hacc[0][ct_], 0, 0, 0); \
      hacc[0][ct_] = __builtin_amdgcn_mfma_f32_16x16x32_bf16(a0l_.s, bh_.s, hacc[0][ct_], 0, 0, 0); \
      hacc[0][ct_] = __builtin_amdgcn_mfma_f32_16x16x32_bf16(a0h_.s, bh_.s, hacc[0][ct_], 0, 0, 0); \
      hacc[1][ct_] = __builtin_amdgcn_mfma_f32_16x16x32_bf16(a1h_.s, bl_.s, hacc[1][ct_], 0, 0, 0); \
      hacc[1][ct_] = __builtin_amdgcn_mfma_f32_16x16x32_bf16(a1l_.s, bh_.s, hacc[1][ct_], 0, 0, 0); \
      hacc[1][ct_] = __builtin_amdgcn_mfma_f32_16x16x32_bf16(a1h_.s, bh_.s, hacc[1][ct_], 0, 0, 0); \
    }                                                                            \
  } while (0)

#define Z_EPI(ZACC, BIASP)                                                       \
  do {                                                                           \
    _Pragma("unroll")                                                            \
    for (int ct_ = 0; ct_ < 8; ++ct_) {                                          \
      int col_ = ct_ * 16 + li;                                                  \
      float bv_ = (BIASP)[col_];                                                 \
      _Pragma("unroll")                                                          \
      for (int sub_ = 0; sub_ < 2; ++sub_) {                                     \
        _Pragma("unroll")                                                        \
        for (int r_ = 0; r_ < 4; ++r_) {                                         \
          float v_ = (ZACC)[sub_][ct_][r_] + bv_;                                \
          v_ = v_ >= 0.f ? v_ : 0.01f * v_;                                      \
          int row_ = w * 32 + sub_ * 16 + lg * 4 + r_;                           \
          int byte_ = row_ * 256 + col_ * 2;                                     \
          byte_ ^= (row_ & 7) << 4;                                              \
          unsigned int u_ = __float_as_uint(v_);                                 \
          *(unsigned short*)((char*)z_hi + byte_) = (unsigned short)(u_ >> 16);  \
          float lo_ = v_ - __uint_as_float(u_ & 0xFFFF0000u);                    \
          *(unsigned short*)((char*)z_lo + byte_) = (unsigned short)(__float_as_uint(lo_) >> 16); \
        }                                                                        \
      }                                                                          \
    }                                                                            \
  } while (0)

// phase B: hacc += z @ Win[SLICE*128 .. +127], 4 K-tiles, fully unrolled,
// 1-deep prefetch of the next Win tile.
#define PHASE_B(SLICE)                                                           \
  do {                                                                           \
    const unsigned short* qh0_ = Wt + OFF_WIN_HI + cr0 * 512 + (SLICE) * 128 + c0 * 8; \
    const unsigned short* ql0_ = Wt + OFF_WIN_LO + cr0 * 512 + (SLICE) * 128 + c0 * 8; \
    const unsigned short* qh1_ = Wt + OFF_WIN_HI + cr1 * 512 + (SLICE) * 128 + c0 * 8; \
    const unsigned short* ql1_ = Wt + OFF_WIN_LO + cr1 * 512 + (SLICE) * 128 + c0 * 8; \
    uint4 wA0_ = *(const uint4*)(qh0_), wA1_ = *(const uint4*)(ql0_);            \
    uint4 wA2_ = *(const uint4*)(qh1_), wA3_ = *(const uint4*)(ql1_);            \
    uint4 wB0_, wB1_, wB2_, wB3_;                                                \
    STORE_BT(wA0_, wA1_, wA2_, wA3_);                                            \
    lgkm0_barrier();                                                             \
    wB0_ = *(const uint4*)(qh0_ + 32); wB1_ = *(const uint4*)(ql0_ + 32);        \
    wB2_ = *(const uint4*)(qh1_ + 32); wB3_ = *(const uint4*)(ql1_ + 32);        \
    MFMA_B(0);                                                                   \
    fence_barrier();                                                             \
    STORE_BT(wB0_, wB1_, wB2_, wB3_);                                            \
    lgkm0_barrier();                                                             \
    wA0_ = *(const uint4*)(qh0_ + 64); wA1_ = *(const uint4*)(ql0_ + 64);        \
    wA2_ = *(const uint4*)(qh1_ + 64); wA3_ = *(const uint4*)(ql1_ + 64);        \
    MFMA_B(1);                                                                   \
    fence_barrier();                                                             \
    STORE_BT(wA0_, wA1_, wA2_, wA3_);                                            \
    lgkm0_barrier();                                                             \
    wB0_ = *(const uint4*)(qh0_ + 96); wB1_ = *(const uint4*)(ql0_ + 96);        \
    wB2_ = *(const uint4*)(qh1_ + 96); wB3_ = *(const uint4*)(ql1_ + 96);        \
    MFMA_B(2);                                                                   \
    fence_barrier();                                                             \
    STORE_BT(wB0_, wB1_, wB2_, wB3_);                                            \
    lgkm0_barrier();                                                             \
    MFMA_B(3);                                                                   \
    fence_barrier();                                                             \
  } while (0)

  f32x4 hacc[2][8];
#pragma unroll
  for (int a = 0; a < 2; ++a)
#pragma unroll
    for (int b = 0; b < 8; ++b) hacc[a][b] = (f32x4)0.f;

  // ---- big segments: des (s=0), tweet (s=1); K=768 = 24 K-tiles, pipelined ----
#pragma unroll
  for (int s = 0; s < 2; ++s) {
    const int off = (s == 0) ? 785 : 6;
    const unsigned short* wh = Wt + (s == 0 ? OFF_DES_HI : OFF_TW_HI);
    const unsigned short* wl = Wt + (s == 0 ? OFF_DES_LO : OFF_TW_LO);
    const float* bias = (s == 0) ? bdes : btw;

    const float* xr0 = xrow0 + off + lg * 8;
    const float* xr1 = xrow1 + off + lg * 8;
    const unsigned short* ph0 = wh + cr0 * 768 + c0 * 8;
    const unsigned short* pl0 = wl + cr0 * 768 + c0 * 8;
    const unsigned short* ph1 = wh + cr1 * 768 + c0 * 8;
    const unsigned short* pl1 = wl + cr1 * 768 + c0 * 8;

    f32x4 zacc[2][8];
#pragma unroll
    for (int a = 0; a < 2; ++a)
#pragma unroll
      for (int b = 0; b < 8; ++b) zacc[a][b] = (f32x4)0.f;

    uint4 bA0, bA1, bA2, bA3, bB0, bB1, bB2, bB3;
    float fA0[8], fA1[8], fB0[8], fB1[8];

    // prologue: issue kt=0 (W first, then x, so W-waits don't drain x)
    bA0 = *(const uint4*)(ph0); bA1 = *(const uint4*)(pl0);
    bA2 = *(const uint4*)(ph1); bA3 = *(const uint4*)(pl1);
#pragma unroll
    for (int j = 0; j < 8; ++j) { fA0[j] = xr0[j]; fA1[j] = xr1[j]; }

    for (int kt = 0; kt < 24; kt += 2) {
      // even K-tile: consume A-regs, prefetch kt+1 into B-regs
      STORE_BT(bA0, bA1, bA2, bA3);
      lgkm0_barrier();
      {
        const int ko = (kt + 1) * 32;
        bB0 = *(const uint4*)(ph0 + ko); bB1 = *(const uint4*)(pl0 + ko);
        bB2 = *(const uint4*)(ph1 + ko); bB3 = *(const uint4*)(pl1 + ko);
#pragma unroll
        for (int j = 0; j < 8; ++j) { fB0[j] = xr0[ko + j]; fB1[j] = xr1[ko + j]; }
      }
      MFMA_A(fA0, fA1, zacc);
      fence_barrier();
      // odd K-tile: consume B-regs, prefetch kt+2 into A-regs
      STORE_BT(bB0, bB1, bB2, bB3);
      lgkm0_barrier();
      if (kt + 2 < 24) {
        const int ko = (kt + 2) * 32;
        bA0 = *(const uint4*)(ph0 + ko); bA1 = *(const uint4*)(pl0 + ko);
        bA2 = *(const uint4*)(ph1 + ko); bA3 = *(const uint4*)(pl1 + ko);
#pragma unroll
        for (int j = 0; j < 8; ++j) { fA0[j] = xr0[ko + j]; fA1[j] = xr1[ko + j]; }
      }
      MFMA_A(fB0, fB1, zacc);
      fence_barrier();
    }
    Z_EPI(zacc, bias);   // z is wave-private: no barrier needed for z itself
    PHASE_B(s);
  }

  // ---- small segments: num (K=6), cat (K=11); single padded K-tile each ----
#pragma unroll
  for (int u = 0; u < 2; ++u) {
    const int offu = (u == 0) ? 0 : 774;
    const int Ksu = (u == 0) ? 6 : 11;
    const unsigned short* wh = Wt + (u == 0 ? OFF_NUM_HI : OFF_CAT_HI);
    const unsigned short* wl = Wt + (u == 0 ? OFF_NUM_LO : OFF_CAT_LO);
    const float* biasu = (u == 0) ? bnum : bcat;
    const float* xr0 = xrow0 + offu + lg * 8;
    const float* xr1 = xrow1 + offu + lg * 8;

    uint4 s0 = *(const uint4*)(wh + cr0 * 32 + c0 * 8);
    uint4 s1 = *(const uint4*)(wl + cr0 * 32 + c0 * 8);
    uint4 s2 = *(const uint4*)(wh + cr1 * 32 + c0 * 8);
    uint4 s3 = *(const uint4*)(wl + cr1 * 32 + c0 * 8);
    float f0[8], f1[8];
#pragma unroll
    for (int j = 0; j < 8; ++j) { f0[j] = xr0[j]; f1[j] = xr1[j]; }
#pragma unroll
    for (int j = 0; j < 8; ++j)
      if (lg * 8 + j >= Ksu) { f0[j] = 0.f; f1[j] = 0.f; }

    f32x4 zacc[2][8];
#pragma unroll
    for (int a = 0; a < 2; ++a)
#pragma unroll
      for (int b = 0; b < 8; ++b) zacc[a][b] = (f32x4)0.f;

    STORE_BT(s0, s1, s2, s3);
    lgkm0_barrier();
    MFMA_A(f0, f1, zacc);
    fence_barrier();
    Z_EPI(zacc, biasu);
    PHASE_B(u + 2);
  }

  // epilogue: + b_in, PReLU, store
#pragma unroll
  for (int ct = 0; ct < 8; ++ct) {
    int col = ct * 16 + li;
    float bi = bin[col];
    float p = pa[col];
#pragma unroll
    for (int sub = 0; sub < 2; ++sub) {
#pragma unroll
      for (int r = 0; r < 4; ++r) {
        int node = node0 + w * 32 + sub * 16 + lg * 4 + r;
        if (node < NN) {
          float v = hacc[sub][ct][r] + bi;
          v = v >= 0.f ? v : p * v;
          h0[(size_t)node * HD + col] = v;
        }
      }
    }
  }

#undef STORE_BT
#undef MFMA_A
#undef MFMA_B
#undef Z_EPI
#undef PHASE_B
}

// ---------------- layer GEMM: hin @ [root|rel0|rel1] (MFMA split-bf16) ----------------
// 64 rows/block, 4 waves: wave = 64 rows x 96 cols (of 384).
// Raw barriers + 1-deep ping-pong prefetch of the A (hin) row fragments.
__global__ __launch_bounds__(256, 2) void k_rgemm(
    const float* __restrict__ hin, const unsigned short* __restrict__ wl_hi,
    const unsigned short* __restrict__ wl_lo, const float* __restrict__ bias,
    float* __restrict__ base, float* __restrict__ mh) {
  __shared__ unsigned short bt_hi[384 * 32], bt_lo[384 * 32];  // 24KB + 24KB

  const int t = threadIdx.x;
  const int node0 = blockIdx.x * 64;
  const int w = t >> 6, lane = t & 63;
  const int li = lane & 15, lg = lane >> 4;

  const float* ab[4];
#pragma unroll
  for (int sub = 0; sub < 4; ++sub) {
    int node = node0 + sub * 16 + li;
    int nd = node < NN ? node : NN - 1;
    ab[sub] = hin + (size_t)nd * HD + lg * 8;
  }

  f32x4 acc[4][6];
#pragma unroll
  for (int a = 0; a < 4; ++a)
#pragma unroll
    for (int b = 0; b < 6; ++b) acc[a][b] = (f32x4)0.f;

// stage B tile [384][32] hi/lo in two halves (keeps reg peak low)
#define RG_STAGE(KT)                                                             \
  do {                                                                           \
    _Pragma("unroll")                                                            \
    for (int h_ = 0; h_ < 2; ++h_) {                                             \
      uint4 sh_[3], sl_[3];                                                      \
      _Pragma("unroll")                                                          \
      for (int j_ = 0; j_ < 3; ++j_) {                                           \
        int cid_ = t + (h_ * 3 + j_) * 256;                                      \
        int cr_ = cid_ >> 2, c_ = cid_ & 3;                                      \
        sh_[j_] = *(const uint4*)(wl_hi + cr_ * 128 + (KT) * 32 + c_ * 8);       \
        sl_[j_] = *(const uint4*)(wl_lo + cr_ * 128 + (KT) * 32 + c_ * 8);       \
      }                                                                          \
      _Pragma("unroll")                                                          \
      for (int j_ = 0; j_ < 3; ++j_) {                                           \
        int cid_ = t + (h_ * 3 + j_) * 256;                                      \
        int cr_ = cid_ >> 2, c_ = cid_ & 3;                                      \
        unsigned b_ = cr_ * 64 + ((c_ ^ ((cr_ >> 1) & 3)) << 4);                 \
        *(uint4*)((char*)bt_hi + b_) = sh_[j_];                                  \
        *(uint4*)((char*)bt_lo + b_) = sl_[j_];                                  \
      }                                                                          \
    }                                                                            \
  } while (0)

#define RG_LOADA(KT, F)                                                          \
  do {                                                                           \
    _Pragma("unroll")                                                            \
    for (int sub_ = 0; sub_ < 4; ++sub_) {                                       \
      _Pragma("unroll")                                                          \
      for (int j_ = 0; j_ < 8; ++j_) (F)[sub_][j_] = ab[sub_][(KT) * 32 + j_];   \
    }                                                                            \
  } while (0)

#define RG_MFMA(F)                                                               \
  do {                                                                           \
    Frag ah_[4], al_[4];                                                         \
    _Pragma("unroll")                                                            \
    for (int sub_ = 0; sub_ < 4; ++sub_)                                         \
      _Pragma("unroll")                                                          \
      for (int q_ = 0; q_ < 4; ++q_)                                             \
        cvt_pair((F)[sub_][2 * q_], (F)[sub_][2 * q_ + 1], ah_[sub_].u[q_], al_[sub_].u[q_]); \
    _Pragma("unroll")                                                            \
    for (int ct_ = 0; ct_ < 6; ++ct_) {                                          \
      int colrow_ = w * 96 + ct_ * 16 + li;                                      \
      int byte_ = colrow_ * 64 + (lg << 4);                                      \
      byte_ ^= ((colrow_ >> 1) & 3) << 4;                                        \
      Frag bh_, bl_;                                                             \
      bh_.v = *(const uint4*)((char*)bt_hi + byte_);                             \
      bl_.v = *(const uint4*)((char*)bt_lo + byte_);                             \
      _Pragma("unroll")                                                          \
      for (int sub_ = 0; sub_ < 4; ++sub_) {                                     \
        acc[sub_][ct_] = __builtin_amdgcn_mfma_f32_16x16x32_bf16(ah_[sub_].s, bl_.s, acc[sub_][ct_], 0, 0, 0); \
        acc[sub_][ct_] = __builtin_amdgcn_mfma_f32_16x16x32_bf16(al_[sub_].s, bh_.s, acc[sub_][ct_], 0, 0, 0); \
        acc[sub_][ct_] = __builtin_amdgcn_mfma_f32_16x16x32_bf16(ah_[sub_].s, bh_.s, acc[sub_][ct_], 0, 0, 0); \
      }                                                                          \
    }                                                                            \
  } while (0)

  float fA[4][8], fB[4][8];
  RG_LOADA(0, fA);

  RG_STAGE(0);
  RG_LOADA(1, fB);
  lgkm0_barrier();
  RG_MFMA(fA);
  fence_barrier();

  RG_STAGE(1);
  RG_LOADA(2, fA);
  lgkm0_barrier();
  RG_MFMA(fB);
  fence_barrier();

  RG_STAGE(2);
  RG_LOADA(3, fB);
  lgkm0_barrier();
  RG_MFMA(fA);
  fence_barrier();

  RG_STAGE(3);
  lgkm0_barrier();
  RG_MFMA(fB);

#undef RG_STAGE
#undef RG_LOADA
#undef RG_MFMA

  // epilogue
#pragma unroll
  for (int ct = 0; ct < 6; ++ct) {
    int gcol = w * 96 + ct * 16 + li;
    float bv = 0.f;
    float* dp;
    int lc;
    if (gcol < 128) { bv = bias[gcol]; dp = base; lc = gcol; }
    else if (gcol < 256) { dp = mh; lc = gcol - 128; }
    else { dp = mh + (size_t)NN * HD; lc = gcol - 256; }
#pragma unroll
    for (int sub = 0; sub < 4; ++sub) {
#pragma unroll
      for (int r = 0; r < 4; ++r) {
        int node = node0 + sub * 16 + lg * 4 + r;
        if (node < NN) dp[(size_t)node * HD + lc] = acc[sub][ct][r] + bv;
      }
    }
  }
}

// ---------------- aggregation ----------------
__global__ __launch_bounds__(256) void k_aggregate(
    float* __restrict__ io, const float* __restrict__ mh,
    const int* __restrict__ row_ptr, const int* __restrict__ cnt2,
    const int* __restrict__ entries) {
  int i = blockIdx.x * 4 + (threadIdx.x >> 6);
  int l = threadIdx.x & 63;
  if (i >= NN) return;
  int rs = row_ptr[i], re = row_ptr[i + 1];
  int c0 = cnt2[i], c1 = cnt2[NN + i];
  float inv0 = 1.f / (float)(c0 > 0 ? c0 : 1);
  float inv1 = 1.f / (float)(c1 > 0 ? c1 : 1);
  float a0 = 0, a1 = 0, b0 = 0, b1 = 0;
  int e = rs;
  for (; e + 1 < re; e += 2) {
    int ent0 = entries[e], ent1 = entries[e + 1];
    const float* r0 = mh + (((size_t)(ent0 >> 20)) * NN + (ent0 & 0xFFFFF)) * HD;
    const float* r1 = mh + (((size_t)(ent1 >> 20)) * NN + (ent1 & 0xFFFFF)) * HD;
    float v00 = r0[l], v01 = r0[l + 64];
    float v10 = r1[l], v11 = r1[l + 64];
    if (ent0 >> 20) { b0 += v00; b1 += v01; } else { a0 += v00; a1 += v01; }
    if (ent1 >> 20) { b0 += v10; b1 += v11; } else { a0 += v10; a1 += v11; }
  }
  if (e < re) {
    int ent = entries[e];
    const float* r0 = mh + (((size_t)(ent >> 20)) * NN + (ent & 0xFFFFF)) * HD;
    float v0 = r0[l], v1 = r0[l + 64];
    if (ent >> 20) { b0 += v0; b1 += v1; } else { a0 += v0; a1 += v1; }
  }
  io[(size_t)i * HD + l] += a0 * inv0 + b0 * inv1;
  io[(size_t)i * HD + l + 64] += a1 * inv0 + b1 * inv1;
}

// ---------------- final linear (MFMA, in-place) ----------------
// 64 rows/block, 4 waves in 2x2: wave = 32 rows x 64 cols.
// Raw barriers + 1-deep ping-pong prefetch of the A (io) row fragments.
__global__ __launch_bounds__(256, 2) void k_cls2(
    float* __restrict__ io, const unsigned short* __restrict__ Wt,
    const float* __restrict__ b) {
  __shared__ unsigned short bt_hi[128 * 32], bt_lo[128 * 32];  // 8KB + 8KB

  const int t = threadIdx.x;
  const int node0 = blockIdx.x * 64;
  const int w = t >> 6, lane = t & 63;
  const int li = lane & 15, lg = lane >> 4;
  const int wr = w >> 1, wc = w & 1;

  int nodeA0 = node0 + wr * 32 + li; int nd0 = nodeA0 < NN ? nodeA0 : NN - 1;
  int nodeA1 = nodeA0 + 16;          int nd1 = nodeA1 < NN ? nodeA1 : NN - 1;
  const float* ap0 = io + (size_t)nd0 * HD + lg * 8;
  const float* ap1 = io + (size_t)nd1 * HD + lg * 8;

  f32x4 acc[2][4];
#pragma unroll
  for (int a = 0; a < 2; ++a)
#pragma unroll
    for (int bq = 0; bq < 4; ++bq) acc[a][bq] = (f32x4)0.f;

#define CL_STAGE(KT)                                                             \
  do {                                                                           \
    uint4 sh_[2], sl_[2];                                                        \
    _Pragma("unroll")                                                            \
    for (int j_ = 0; j_ < 2; ++j_) {                                             \
      int cid_ = t + j_ * 256;                                                   \
      int cr_ = cid_ >> 2, c_ = cid_ & 3;                                        \
      sh_[j_] = *(const uint4*)(Wt + OFF_CLS_HI + cr_ * 128 + (KT) * 32 + c_ * 8); \
      sl_[j_] = *(const uint4*)(Wt + OFF_CLS_LO + cr_ * 128 + (KT) * 32 + c_ * 8); \
    }                                                                            \
    _Pragma("unroll")                                                            \
    for (int j_ = 0; j_ < 2; ++j_) {                                             \
      int cid_ = t + j_ * 256;                                                   \
      int cr_ = cid_ >> 2, c_ = cid_ & 3;                                        \
      unsigned b_ = cr_ * 64 + ((c_ ^ ((cr_ >> 1) & 3)) << 4);                   \
      *(uint4*)((char*)bt_hi + b_) = sh_[j_];                                    \
      *(uint4*)((char*)bt_lo + b_) = sl_[j_];                                    \
    }                                                                            \
  } while (0)

#define CL_LOADA(KT, F)                                                          \
  do {                                                                           \
    _Pragma("unroll")                                                            \
    for (int j_ = 0; j_ < 8; ++j_) {                                             \
      (F)[0][j_] = ap0[(KT) * 32 + j_];                                          \
      (F)[1][j_] = ap1[(KT) * 32 + j_];                                          \
    }                                                                            \
  } while (0)

#define CL_MFMA(F)                                                               \
  do {                                                                           \
    Frag ah_[2], al_[2];                                                         \
    _Pragma("unroll")                                                            \
    for (int sub_ = 0; sub_ < 2; ++sub_)                                         \
      _Pragma("unroll")                                                          \
      for (int q_ = 0; q_ < 4; ++q_)                                             \
        cvt_pair((F)[sub_][2 * q_], (F)[sub_][2 * q_ + 1], ah_[sub_].u[q_], al_[sub_].u[q_]); \
    _Pragma("unroll")                                                            \
    for (int ct_ = 0; ct_ < 4; ++ct_) {                                          \
      int colrow_ = wc * 64 + ct_ * 16 + li;                                     \
      int byte_ = colrow_ * 64 + (lg << 4);                                      \
      byte_ ^= ((colrow_ >> 1) & 3) << 4;                                        \
      Frag bh_, bl_;                                                             \
      bh_.v = *(const uint4*)((char*)bt_hi + byte_);                             \
      bl_.v = *(const uint4*)((char*)bt_lo + byte_);                             \
      _Pragma("unroll")                                                          \
      for (int sub_ = 0; sub_ < 2; ++sub_) {                                     \
        acc[sub_][ct_] = __builtin_amdgcn_mfma_f32_16x16x32_bf16(ah_[sub_].s, bl_.s, acc[sub_][ct_], 0, 0, 0); \
        acc[sub_][ct_] = __builtin_amdgcn_mfma_f32_16x16x32_bf16(al_[sub_].s, bh_.s, acc[sub_][ct_], 0, 0, 0); \
        acc[sub_][ct_] = __builtin_amdgcn_mfma_f32_16x16x32_bf16(ah_[sub_].s, bh_.s, acc[sub_][ct_], 0, 0, 0); \
      }                                                                          \
    }                                                                            \
  } while (0)

  float fA[2][8], fB[2][8];
  CL_LOADA(0, fA);

  CL_STAGE(0);
  CL_LOADA(1, fB);
  lgkm0_barrier();
  CL_MFMA(fA);
  fence_barrier();

  CL_STAGE(1);
  CL_LOADA(2, fA);
  lgkm0_barrier();
  CL_MFMA(fB);
  fence_barrier();

  CL_STAGE(2);
  CL_LOADA(3, fB);
  lgkm0_barrier();
  CL_MFMA(fA);
  fence_barrier();

  CL_STAGE(3);
  lgkm0_barrier();
  CL_MFMA(fB);

#undef CL_STAGE
#undef CL_LOADA
#undef CL_MFMA

  __syncthreads();  // all A-reads of this block's rows done before in-place writes
#pragma unroll
  for (int ct = 0; ct < 4; ++ct) {
    int col = wc * 64 + ct * 16 + li;
    float bv = b[col];
#pragma unroll
    for (int sub = 0; sub < 2; ++sub) {
#pragma unroll
      for (int r = 0; r < 4; ++r) {
        int node = node0 + wr * 32 + sub * 16 + lg * 4 + r;
        if (node < NN) io[(size_t)node * HD + col] = acc[sub][ct][r] + bv;
      }
    }
  }
}

extern "C" void kernel_launch(void* const* d_in, const int* in_sizes, int n_in,
                              void* d_out, int out_size, void* d_ws, size_t ws_size,
                              hipStream_t stream) {
  const float* x    = (const float*)d_in[0];
  const int* ei     = (const int*)d_in[1];
  const int* et     = (const int*)d_in[2];
  const float* Wdes = (const float*)d_in[3];
  const float* bdes = (const float*)d_in[4];
  const float* Wtw  = (const float*)d_in[5];
  const float* btw  = (const float*)d_in[6];
  const float* Wnum = (const float*)d_in[7];
  const float* bnum = (const float*)d_in[8];
  const float* Wcat = (const float*)d_in[9];
  const float* bcat = (const float*)d_in[10];
  const float* Win  = (const float*)d_in[11];
  const float* bin  = (const float*)d_in[12];
  const float* pa   = (const float*)d_in[13];
  const float* root1 = (const float*)d_in[14];
  const float* rel1  = (const float*)d_in[15];
  const float* bias1 = (const float*)d_in[16];
  const float* root2 = (const float*)d_in[17];
  const float* rel2  = (const float*)d_in[18];
  const float* bias2 = (const float*)d_in[19];
  const float* Wcls  = (const float*)d_in[20];
  const float* bcls  = (const float*)d_in[21];
  float* out = (float*)d_out;

  char* p = (char*)d_ws;
  float* mh = (float*)p;      p += (size_t)2 * NN * HD * 4;   // 102.4 MB
  float* hB = (float*)p;      p += (size_t)NN * HD * 4;       // 51.2 MB
  int* row_ptr = (int*)p;     p += ((size_t)NN + 4) * 4;
  int* cnt2 = (int*)p;        p += (size_t)2 * NN * 4;
  int* fillpos = (int*)p;     p += (size_t)NN * 4;
  int* entries = (int*)p;     p += (size_t)EE * 4;
  int* bsum = (int*)p;        p += 512;
  unsigned short* Wt = (unsigned short*)p;  p += (size_t)WT_SITES * 2 * 2;

  // weight pre-convert (independent of everything else)
  k_prepw<<<(WT_SITES + 255) / 256, 256, 0, stream>>>(
      Wdes, Wtw, Wnum, Wcat, Win, root1, rel1, root2, rel2, Wcls, Wt);

  // CSR build
  hipMemsetAsync(cnt2, 0, (size_t)3 * NN * 4, stream);  // cnt2 + fillpos
  k_count<<<EE / 256, 256, 0, stream>>>(ei, et, cnt2);
  int nb = (NN + 1023) / 1024;
  k_scan1<<<nb, 256, 0, stream>>>(cnt2, row_ptr, bsum);
  k_scan2<<<1, 128, 0, stream>>>(bsum, nb);
  k_scan3<<<(NN + 1 + 255) / 256, 256, 0, stream>>>(row_ptr, bsum);
  k_fill<<<EE / 256, 256, 0, stream>>>(ei, et, row_ptr, fillpos, entries);

  const int nblkP = (NN + 127) / 128;  // 782
  const int nblk = (NN + 63) / 64;     // 1563
  // h0 -> d_out
  k_proj2<<<nblkP, 256, 0, stream>>>(x, bdes, btw, bnum, bcat, bin, pa, Wt, out);
  // layer 1
  k_rgemm<<<nblk, 256, 0, stream>>>(out, Wt + OFF_L1_HI, Wt + OFF_L1_LO, bias1, hB, mh);
  k_aggregate<<<NN / 4, 256, 0, stream>>>(hB, mh, row_ptr, cnt2, entries);
  // layer 2
  k_rgemm<<<nblk, 256, 0, stream>>>(hB, Wt + OFF_L2_HI, Wt + OFF_L2_LO, bias2, out, mh);
  k_aggregate<<<NN / 4, 256, 0, stream>>>(out, mh, row_ptr, cnt2, entries);
  // classifier (MFMA, in-place)
  k_cls2<<<nblk, 256, 0, stream>>>(out, Wt, bcls);
}

// Round 3
// 1048.620 us; speedup vs baseline: 1.6842x; 1.0134x over previous
//
#include <hip/hip_runtime.h>
#include <cstdint>
#include <cstddef>

#define NN 100000
#define EE 1600000
#define XDIM 1553
#define HD 128

typedef __attribute__((ext_vector_type(8))) short short8;
typedef __attribute__((ext_vector_type(4))) float f32x4;

union Frag { unsigned int u[4]; short8 s; uint4 v; };

// weight area offsets (ushort units); hi/lo are separate regions
#define OFF_DES_HI 0
#define OFF_DES_LO 98304
#define OFF_TW_HI  196608
#define OFF_TW_LO  294912
#define OFF_NUM_HI 393216
#define OFF_NUM_LO 397312
#define OFF_CAT_HI 401408
#define OFF_CAT_LO 405504
#define OFF_WIN_HI 409600
#define OFF_WIN_LO 475136
#define OFF_L1_HI  540672
#define OFF_L1_LO  589824
#define OFF_L2_HI  638976
#define OFF_L2_LO  688128
#define OFF_CLS_HI 737280
#define OFF_CLS_LO 753664
#define WT_SITES   385024   // (col,k) sites; each writes hi+lo

// hi = trunc-bf16(f), lo = trunc-bf16(f - hi). Packed: 2 elems -> 1 u32 via v_perm.
__device__ __forceinline__ void cvt_pair(float f0, float f1,
                                         unsigned int& hi, unsigned int& lo) {
  unsigned int u0 = __float_as_uint(f0), u1 = __float_as_uint(f1);
  hi = __builtin_amdgcn_perm(u1, u0, 0x07060302u);
  float l0 = f0 - __uint_as_float(u0 & 0xFFFF0000u);
  float l1 = f1 - __uint_as_float(u1 & 0xFFFF0000u);
  lo = __builtin_amdgcn_perm(__float_as_uint(l1), __float_as_uint(l0), 0x07060302u);
}

// raw barriers: no vmcnt drain (prefetched global loads ride across);
// lgkm0 variant publishes ds_writes before the barrier.
__device__ __forceinline__ void fence_barrier() {
  asm volatile("" ::: "memory");
  __builtin_amdgcn_s_barrier();
  asm volatile("" ::: "memory");
}
__device__ __forceinline__ void lgkm0_barrier() {
  asm volatile("s_waitcnt lgkmcnt(0)" ::: "memory");
  __builtin_amdgcn_s_barrier();
  asm volatile("" ::: "memory");
}

// ---------------- weight pre-convert/transpose (runs once, tiny) ----------------
__global__ __launch_bounds__(256) void k_prepw(
    const float* __restrict__ Wdes, const float* __restrict__ Wtw,
    const float* __restrict__ Wnum, const float* __restrict__ Wcat,
    const float* __restrict__ Win,  const float* __restrict__ root1,
    const float* __restrict__ rel1, const float* __restrict__ root2,
    const float* __restrict__ rel2, const float* __restrict__ Wcls,
    unsigned short* __restrict__ Wt) {
  int id = blockIdx.x * 256 + threadIdx.x;
  if (id >= WT_SITES) return;
  const float* src; int K, Kpad, dhi, dlo, local;
  if (id < 98304)       { src=Wdes;        K=768; Kpad=768; dhi=OFF_DES_HI;       dlo=OFF_DES_LO;       local=id; }
  else if (id < 196608) { src=Wtw;         K=768; Kpad=768; dhi=OFF_TW_HI;        dlo=OFF_TW_LO;        local=id-98304; }
  else if (id < 200704) { src=Wnum;        K=6;   Kpad=32;  dhi=OFF_NUM_HI;       dlo=OFF_NUM_LO;       local=id-196608; }
  else if (id < 204800) { src=Wcat;        K=11;  Kpad=32;  dhi=OFF_CAT_HI;       dlo=OFF_CAT_LO;       local=id-200704; }
  else if (id < 270336) { src=Win;         K=512; Kpad=512; dhi=OFF_WIN_HI;       dlo=OFF_WIN_LO;       local=id-204800; }
  else if (id < 286720) { src=root1;       K=128; Kpad=128; dhi=OFF_L1_HI;        dlo=OFF_L1_LO;        local=id-270336; }
  else if (id < 303104) { src=rel1;        K=128; Kpad=128; dhi=OFF_L1_HI+16384;  dlo=OFF_L1_LO+16384;  local=id-286720; }
  else if (id < 319488) { src=rel1+16384;  K=128; Kpad=128; dhi=OFF_L1_HI+32768;  dlo=OFF_L1_LO+32768;  local=id-303104; }
  else if (id < 335872) { src=root2;       K=128; Kpad=128; dhi=OFF_L2_HI;        dlo=OFF_L2_LO;        local=id-319488; }
  else if (id < 352256) { src=rel2;        K=128; Kpad=128; dhi=OFF_L2_HI+16384;  dlo=OFF_L2_LO+16384;  local=id-335872; }
  else if (id < 368640) { src=rel2+16384;  K=128; Kpad=128; dhi=OFF_L2_HI+32768;  dlo=OFF_L2_LO+32768;  local=id-352256; }
  else                  { src=Wcls;        K=128; Kpad=128; dhi=OFF_CLS_HI;       dlo=OFF_CLS_LO;       local=id-368640; }
  int col = local / Kpad;
  int k = local - col * Kpad;
  float v = (k < K) ? src[(size_t)k * 128 + col] : 0.f;
  unsigned int u = __float_as_uint(v);
  float lo = v - __uint_as_float(u & 0xFFFF0000u);
  Wt[dhi + col * Kpad + k] = (unsigned short)(u >> 16);
  Wt[dlo + col * Kpad + k] = (unsigned short)(__float_as_uint(lo) >> 16);
}

// ---------------- CSR build ----------------
__global__ __launch_bounds__(256) void k_count(const int* __restrict__ ei,
                                               const int* __restrict__ et,
                                               int* __restrict__ cnt2) {
  int e = blockIdx.x * 256 + threadIdx.x;
  if (e >= EE) return;
  atomicAdd(&cnt2[et[e] * NN + ei[EE + e]], 1);
}

__global__ __launch_bounds__(256) void k_scan1(const int* __restrict__ cnt2,
                                               int* __restrict__ row_ptr,
                                               int* __restrict__ bsum) {
  __shared__ int sums[256];
  int t = threadIdx.x;
  int base = blockIdx.x * 1024 + t * 4;
  int v[4]; int s = 0;
#pragma unroll
  for (int j = 0; j < 4; ++j) {
    int idx = base + j;
    v[j] = (idx < NN) ? (cnt2[idx] + cnt2[NN + idx]) : 0;
    s += v[j];
  }
  sums[t] = s;
  __syncthreads();
  for (int d = 1; d < 256; d <<= 1) {
    int val = (t >= d) ? sums[t - d] : 0;
    __syncthreads();
    sums[t] += val;
    __syncthreads();
  }
  int excl = sums[t] - s;
  if (t == 255) bsum[blockIdx.x] = sums[t];
  int run = excl;
#pragma unroll
  for (int j = 0; j < 4; ++j) {
    int idx = base + j;
    if (idx < NN) row_ptr[idx] = run;
    run += v[j];
  }
}

__global__ __launch_bounds__(128) void k_scan2(int* __restrict__ bsum, int nb) {
  __shared__ int s[128];
  int t = threadIdx.x;
  int v = (t < nb) ? bsum[t] : 0;
  s[t] = v;
  __syncthreads();
  for (int d = 1; d < 128; d <<= 1) {
    int val = (t >= d) ? s[t - d] : 0;
    __syncthreads();
    s[t] += val;
    __syncthreads();
  }
  if (t < nb) bsum[t] = s[t] - v;
}

__global__ __launch_bounds__(256) void k_scan3(int* __restrict__ row_ptr,
                                               const int* __restrict__ bsum) {
  int idx = blockIdx.x * 256 + threadIdx.x;
  if (idx < NN) row_ptr[idx] += bsum[idx >> 10];
  if (idx == NN) row_ptr[NN] = EE;
}

__global__ __launch_bounds__(256) void k_fill(const int* __restrict__ ei,
                                              const int* __restrict__ et,
                                              const int* __restrict__ row_ptr,
                                              int* __restrict__ fillpos,
                                              int* __restrict__ entries) {
  int e = blockIdx.x * 256 + threadIdx.x;
  if (e >= EE) return;
  int src = ei[e];
  int dst = ei[EE + e];
  int r = et[e];
  int pos = atomicAdd(&fillpos[dst], 1);
  entries[row_ptr[dst] + pos] = src | (r << 20);
}

// ---------------- fused projection (MFMA, split-bf16, pipelined, raw barriers) ----
// 64 nodes/block, 4 waves, wave = 16 rows x 128 cols. 3 blocks/CU (48KB LDS,
// VGPR kept under the 3-waves/SIMD ceiling). X prefetch depth-3 (HBM ~900cy),
// W ping-pong depth-1 (L2-hot). Raw barriers: no vmcnt drain at syncs.
__global__ __launch_bounds__(256, 3) void k_proj2(
    const float* __restrict__ x,
    const float* __restrict__ bdes, const float* __restrict__ btw,
    const float* __restrict__ bnum, const float* __restrict__ bcat,
    const float* __restrict__ bin,  const float* __restrict__ pa,
    const unsigned short* __restrict__ Wt, float* __restrict__ h0) {
  __shared__ unsigned short bt_hi[128 * 32], bt_lo[128 * 32];   // 8KB + 8KB
  __shared__ unsigned short z_hi[64 * 128], z_lo[64 * 128];     // 16KB + 16KB

  const int t = threadIdx.x;
  const int node0 = blockIdx.x * 64;
  const int w = t >> 6, lane = t & 63;
  const int li = lane & 15, lg = lane >> 4;

  // B-staging constants (loop-invariant per thread)
  const int cr0 = t >> 2, c0 = t & 3;
  const int cr1 = cr0 + 64;
  const unsigned stb0 = cr0 * 64 + ((c0 ^ ((cr0 >> 1) & 3)) << 4);
  const unsigned stb1 = cr1 * 64 + ((c0 ^ ((cr1 >> 1) & 3)) << 4);

  // one A-row per (wave, li)
  const int rowA = w * 16 + li;
  int nodeA = node0 + rowA;
  int ndA = nodeA < NN ? nodeA : NN - 1;
  const float* xrow = x + (size_t)ndA * XDIM;

#define STORE_BT(SH0, SL0, SH1, SL1)              \
  do {                                            \
    *(uint4*)((char*)bt_hi + stb0) = (SH0);       \
    *(uint4*)((char*)bt_lo + stb0) = (SL0);       \
    *(uint4*)((char*)bt_hi + stb1) = (SH1);       \
    *(uint4*)((char*)bt_lo + stb1) = (SL1);       \
  } while (0)

#define CVT_A(F, AH, AL)                                                         \
  do {                                                                           \
    _Pragma("unroll")                                                            \
    for (int q_ = 0; q_ < 4; ++q_)                                               \
      cvt_pair((F)[2 * q_], (F)[2 * q_ + 1], (AH).u[q_], (AL).u[q_]);            \
  } while (0)

#define MFMA8(AH, AL, ACC)                                                       \
  do {                                                                           \
    _Pragma("unroll")                                                            \
    for (int ct_ = 0; ct_ < 8; ++ct_) {                                          \
      int colrow_ = ct_ * 16 + li;                                               \
      int byte_ = colrow_ * 64 + (lg << 4);                                      \
      byte_ ^= ((colrow_ >> 1) & 3) << 4;                                        \
      Frag bh_, bl_;                                                             \
      bh_.v = *(const uint4*)((char*)bt_hi + byte_);                             \
      bl_.v = *(const uint4*)((char*)bt_lo + byte_);                             \
      (ACC)[ct_] = __builtin_amdgcn_mfma_f32_16x16x32_bf16((AH).s, bl_.s, (ACC)[ct_], 0, 0, 0); \
      (ACC)[ct_] = __builtin_amdgcn_mfma_f32_16x16x32_bf16((AL).s, bh_.s, (ACC)[ct_], 0, 0, 0); \
      (ACC)[ct_] = __builtin_amdgcn_mfma_f32_16x16x32_bf16((AH).s, bh_.s, (ACC)[ct_], 0, 0, 0); \
    }                                                                            \
  } while (0)

// one K-tile of phase A: store W tile (cur), barrier, convert X, prefetch
// W(T+1, into next buf) + X(T+3, back into same X buf), MFMA, barrier.
#define TILE(WC0, WC1, WC2, WC3, WN0, WN1, WN2, WN3, XB, T)                      \
  do {                                                                           \
    STORE_BT(WC0, WC1, WC2, WC3);                                                \
    lgkm0_barrier();                                                             \
    Frag ah_, al_;                                                               \
    CVT_A(XB, ah_, al_);                                                         \
    {                                                                            \
      const int kw_ = ((T) + 1) * 32;                                            \
      WN0 = *(const uint4*)(ph0 + kw_); WN1 = *(const uint4*)(pl0 + kw_);        \
      WN2 = *(const uint4*)(ph1 + kw_); WN3 = *(const uint4*)(pl1 + kw_);        \
      int kx_ = (T) + 3; if (kx_ > 23) kx_ = 23; kx_ *= 32;                      \
      _Pragma("unroll")                                                          \
      for (int j_ = 0; j_ < 8; ++j_) XB[j_] = xr[kx_ + j_];                      \
    }                                                                            \
    MFMA8(ah_, al_, zacc);                                                       \
    fence_barrier();                                                             \
  } while (0)

#define MFMA_B(KT)                                                               \
  do {                                                                           \
    Frag ah_, al_;                                                               \
    int byte_ = rowA * 256 + (((KT) * 32 + lg * 8) << 1);                        \
    byte_ ^= (rowA & 7) << 4;                                                    \
    ah_.v = *(const uint4*)((char*)z_hi + byte_);                                \
    al_.v = *(const uint4*)((char*)z_lo + byte_);                                \
    MFMA8(ah_, al_, hacc);                                                       \
  } while (0)

#define Z_EPI(ZACC, BIASP)                                                       \
  do {                                                                           \
    _Pragma("unroll")                                                            \
    for (int ct_ = 0; ct_ < 8; ++ct_) {                                          \
      int col_ = ct_ * 16 + li;                                                  \
      float bv_ = (BIASP)[col_];                                                 \
      _Pragma("unroll")                                                          \
      for (int r_ = 0; r_ < 4; ++r_) {                                           \
        float v_ = (ZACC)[ct_][r_] + bv_;                                        \
        v_ = v_ >= 0.f ? v_ : 0.01f * v_;                                        \
        int row_ = w * 16 + lg * 4 + r_;                                         \
        int byte_ = row_ * 256 + col_ * 2;                                       \
        byte_ ^= (row_ & 7) << 4;                                                \
        unsigned int u_ = __float_as_uint(v_);                                   \
        *(unsigned short*)((char*)z_hi + byte_) = (unsigned short)(u_ >> 16);    \
        float lo_ = v_ - __uint_as_float(u_ & 0xFFFF0000u);                      \
        *(unsigned short*)((char*)z_lo + byte_) = (unsigned short)(__float_as_uint(lo_) >> 16); \
      }                                                                          \
    }                                                                            \
  } while (0)

// phase B: hacc += z @ Win[SLICE*128 .. +127], 4 K-tiles, fully unrolled,
// 1-deep prefetch of the next Win tile.
#define PHASE_B(SLICE)                                                           \
  do {                                                                           \
    const unsigned short* qh0_ = Wt + OFF_WIN_HI + cr0 * 512 + (SLICE) * 128 + c0 * 8; \
    const unsigned short* ql0_ = Wt + OFF_WIN_LO + cr0 * 512 + (SLICE) * 128 + c0 * 8; \
    const unsigned short* qh1_ = Wt + OFF_WIN_HI + cr1 * 512 + (SLICE) * 128 + c0 * 8; \
    const unsigned short* ql1_ = Wt + OFF_WIN_LO + cr1 * 512 + (SLICE) * 128 + c0 * 8; \
    uint4 wA0_ = *(const uint4*)(qh0_), wA1_ = *(const uint4*)(ql0_);            \
    uint4 wA2_ = *(const uint4*)(qh1_), wA3_ = *(const uint4*)(ql1_);            \
    uint4 wB0_, wB1_, wB2_, wB3_;                                                \
    STORE_BT(wA0_, wA1_, wA2_, wA3_);                                            \
    lgkm0_barrier();                                                             \
    wB0_ = *(const uint4*)(qh0_ + 32); wB1_ = *(const uint4*)(ql0_ + 32);        \
    wB2_ = *(const uint4*)(qh1_ + 32); wB3_ = *(const uint4*)(ql1_ + 32);        \
    MFMA_B(0);                                                                   \
    fence_barrier();                                                             \
    STORE_BT(wB0_, wB1_, wB2_, wB3_);                                            \
    lgkm0_barrier();                                                             \
    wA0_ = *(const uint4*)(qh0_ + 64); wA1_ = *(const uint4*)(ql0_ + 64);        \
    wA2_ = *(const uint4*)(qh1_ + 64); wA3_ = *(const uint4*)(ql1_ + 64);        \
    MFMA_B(1);                                                                   \
    fence_barrier();                                                             \
    STORE_BT(wA0_, wA1_, wA2_, wA3_);                                            \
    lgkm0_barrier();                                                             \
    wB0_ = *(const uint4*)(qh0_ + 96); wB1_ = *(const uint4*)(ql0_ + 96);        \
    wB2_ = *(const uint4*)(qh1_ + 96); wB3_ = *(const uint4*)(ql1_ + 96);        \
    MFMA_B(2);                                                                   \
    fence_barrier();                                                             \
    STORE_BT(wB0_, wB1_, wB2_, wB3_);                                            \
    lgkm0_barrier();                                                             \
    MFMA_B(3);                                                                   \
    fence_barrier();                                                             \
  } while (0)

  f32x4 hacc[8];
#pragma unroll
  for (int b = 0; b < 8; ++b) hacc[b] = (f32x4)0.f;

  // ---- big segments: des (s=0), tweet (s=1); K=768 = 24 K-tiles, pipelined ----
#pragma unroll
  for (int s = 0; s < 2; ++s) {
    const int off = (s == 0) ? 785 : 6;
    const unsigned short* wh = Wt + (s == 0 ? OFF_DES_HI : OFF_TW_HI);
    const unsigned short* wl = Wt + (s == 0 ? OFF_DES_LO : OFF_TW_LO);
    const float* bias = (s == 0) ? bdes : btw;

    const float* xr = xrow + off + lg * 8;
    const unsigned short* ph0 = wh + cr0 * 768 + c0 * 8;
    const unsigned short* pl0 = wl + cr0 * 768 + c0 * 8;
    const unsigned short* ph1 = wh + cr1 * 768 + c0 * 8;
    const unsigned short* pl1 = wl + cr1 * 768 + c0 * 8;

    f32x4 zacc[8];
#pragma unroll
    for (int b = 0; b < 8; ++b) zacc[b] = (f32x4)0.f;

    uint4 WA0, WA1, WA2, WA3, WB0, WB1, WB2, WB3;
    float X0[8], X1[8], X2[8];

    // prologue: W tile 0, X tiles 0..2
    WA0 = *(const uint4*)(ph0); WA1 = *(const uint4*)(pl0);
    WA2 = *(const uint4*)(ph1); WA3 = *(const uint4*)(pl1);
#pragma unroll
    for (int j = 0; j < 8; ++j) X0[j] = xr[j];
#pragma unroll
    for (int j = 0; j < 8; ++j) X1[j] = xr[32 + j];
#pragma unroll
    for (int j = 0; j < 8; ++j) X2[j] = xr[64 + j];

    for (int base = 0; base < 24; base += 6) {
      TILE(WA0, WA1, WA2, WA3, WB0, WB1, WB2, WB3, X0, base + 0);
      TILE(WB0, WB1, WB2, WB3, WA0, WA1, WA2, WA3, X1, base + 1);
      TILE(WA0, WA1, WA2, WA3, WB0, WB1, WB2, WB3, X2, base + 2);
      TILE(WB0, WB1, WB2, WB3, WA0, WA1, WA2, WA3, X0, base + 3);
      TILE(WA0, WA1, WA2, WA3, WB0, WB1, WB2, WB3, X1, base + 4);
      TILE(WB0, WB1, WB2, WB3, WA0, WA1, WA2, WA3, X2, base + 5);
    }
    Z_EPI(zacc, bias);   // z is wave-private: no barrier needed for z itself
    PHASE_B(s);
  }

  // ---- small segments: num (K=6), cat (K=11); single padded K-tile each ----
#pragma unroll
  for (int u = 0; u < 2; ++u) {
    const int offu = (u == 0) ? 0 : 774;
    const int Ksu = (u == 0) ? 6 : 11;
    const unsigned short* wh = Wt + (u == 0 ? OFF_NUM_HI : OFF_CAT_HI);
    const unsigned short* wl = Wt + (u == 0 ? OFF_NUM_LO : OFF_CAT_LO);
    const float* biasu = (u == 0) ? bnum : bcat;
    const float* xr = xrow + offu + lg * 8;

    uint4 s0 = *(const uint4*)(wh + cr0 * 32 + c0 * 8);
    uint4 s1 = *(const uint4*)(wl + cr0 * 32 + c0 * 8);
    uint4 s2 = *(const uint4*)(wh + cr1 * 32 + c0 * 8);
    uint4 s3 = *(const uint4*)(wl + cr1 * 32 + c0 * 8);
    float f[8];
#pragma unroll
    for (int j = 0; j < 8; ++j) f[j] = xr[j];
#pragma unroll
    for (int j = 0; j < 8; ++j)
      if (lg * 8 + j >= Ksu) f[j] = 0.f;

    f32x4 zacc[8];
#pragma unroll
    for (int b = 0; b < 8; ++b) zacc[b] = (f32x4)0.f;

    STORE_BT(s0, s1, s2, s3);
    lgkm0_barrier();
    {
      Frag ah_, al_;
      CVT_A(f, ah_, al_);
      MFMA8(ah_, al_, zacc);
    }
    fence_barrier();
    Z_EPI(zacc, biasu);
    PHASE_B(u + 2);
  }

  // epilogue: + b_in, PReLU, store
#pragma unroll
  for (int ct = 0; ct < 8; ++ct) {
    int col = ct * 16 + li;
    float bi = bin[col];
    float p = pa[col];
#pragma unroll
    for (int r = 0; r < 4; ++r) {
      int node = node0 + w * 16 + lg * 4 + r;
      if (node < NN) {
        float v = hacc[ct][r] + bi;
        v = v >= 0.f ? v : p * v;
        h0[(size_t)node * HD + col] = v;
      }
    }
  }

#undef STORE_BT
#undef CVT_A
#undef MFMA8
#undef TILE
#undef MFMA_B
#undef Z_EPI
#undef PHASE_B
}

// ---------------- layer GEMM: hin @ [root|rel0|rel1] (MFMA split-bf16) ----------------
// 64 rows/block, 4 waves: wave = 64 rows x 96 cols (of 384).
// Raw barriers + 1-deep ping-pong prefetch of the A (hin) row fragments.
__global__ __launch_bounds__(256, 2) void k_rgemm(
    const float* __restrict__ hin, const unsigned short* __restrict__ wl_hi,
    const unsigned short* __restrict__ wl_lo, const float* __restrict__ bias,
    float* __restrict__ base, float* __restrict__ mh) {
  __shared__ unsigned short bt_hi[384 * 32], bt_lo[384 * 32];  // 24KB + 24KB

  const int t = threadIdx.x;
  const int node0 = blockIdx.x * 64;
  const int w = t >> 6, lane = t & 63;
  const int li = lane & 15, lg = lane >> 4;

  const float* ab[4];
#pragma unroll
  for (int sub = 0; sub < 4; ++sub) {
    int node = node0 + sub * 16 + li;
    int nd = node < NN ? node : NN - 1;
    ab[sub] = hin + (size_t)nd * HD + lg * 8;
  }

  f32x4 acc[4][6];
#pragma unroll
  for (int a = 0; a < 4; ++a)
#pragma unroll
    for (int b = 0; b < 6; ++b) acc[a][b] = (f32x4)0.f;

// stage B tile [384][32] hi/lo in two halves (keeps reg peak low)
#define RG_STAGE(KT)                                                             \
  do {                                                                           \
    _Pragma("unroll")                                                            \
    for (int h_ = 0; h_ < 2; ++h_) {                                             \
      uint4 sh_[3], sl_[3];                                                      \
      _Pragma("unroll")                                                          \
      for (int j_ = 0; j_ < 3; ++j_) {                                           \
        int cid_ = t + (h_ * 3 + j_) * 256;                                      \
        int cr_ = cid_ >> 2, c_ = cid_ & 3;                                      \
        sh_[j_] = *(const uint4*)(wl_hi + cr_ * 128 + (KT) * 32 + c_ * 8);       \
        sl_[j_] = *(const uint4*)(wl_lo + cr_ * 128 + (KT) * 32 + c_ * 8);       \
      }                                                                          \
      _Pragma("unroll")                                                          \
      for (int j_ = 0; j_ < 3; ++j_) {                                           \
        int cid_ = t + (h_ * 3 + j_) * 256;                                      \
        int cr_ = cid_ >> 2, c_ = cid_ & 3;                                      \
        unsigned b_ = cr_ * 64 + ((c_ ^ ((cr_ >> 1) & 3)) << 4);                 \
        *(uint4*)((char*)bt_hi + b_) = sh_[j_];                                  \
        *(uint4*)((char*)bt_lo + b_) = sl_[j_];                                  \
      }                                                                          \
    }                                                                            \
  } while (0)

#define RG_LOADA(KT, F)                                                          \
  do {                                                                           \
    _Pragma("unroll")                                                            \
    for (int sub_ = 0; sub_ < 4; ++sub_) {                                       \
      _Pragma("unroll")                                                          \
      for (int j_ = 0; j_ < 8; ++j_) (F)[sub_][j_] = ab[sub_][(KT) * 32 + j_];   \
    }                                                                            \
  } while (0)

#define RG_MFMA(F)                                                               \
  do {                                                                           \
    Frag ah_[4], al_[4];                                                         \
    _Pragma("unroll")                                                            \
    for (int sub_ = 0; sub_ < 4; ++sub_)                                         \
      _Pragma("unroll")                                                          \
      for (int q_ = 0; q_ < 4; ++q_)                                             \
        cvt_pair((F)[sub_][2 * q_], (F)[sub_][2 * q_ + 1], ah_[sub_].u[q_], al_[sub_].u[q_]); \
    _Pragma("unroll")                                                            \
    for (int ct_ = 0; ct_ < 6; ++ct_) {                                          \
      int colrow_ = w * 96 + ct_ * 16 + li;                                      \
      int byte_ = colrow_ * 64 + (lg << 4);                                      \
      byte_ ^= ((colrow_ >> 1) & 3) << 4;                                        \
      Frag bh_, bl_;                                                             \
      bh_.v = *(const uint4*)((char*)bt_hi + byte_);                             \
      bl_.v = *(const uint4*)((char*)bt_lo + byte_);                             \
      _Pragma("unroll")                                                          \
      for (int sub_ = 0; sub_ < 4; ++sub_) {                                     \
        acc[sub_][ct_] = __builtin_amdgcn_mfma_f32_16x16x32_bf16(ah_[sub_].s, bl_.s, acc[sub_][ct_], 0, 0, 0); \
        acc[sub_][ct_] = __builtin_amdgcn_mfma_f32_16x16x32_bf16(al_[sub_].s, bh_.s, acc[sub_][ct_], 0, 0, 0); \
        acc[sub_][ct_] = __builtin_amdgcn_mfma_f32_16x16x32_bf16(ah_[sub_].s, bh_.s, acc[sub_][ct_], 0, 0, 0); \
      }                                                                          \
    }                                                                            \
  } while (0)

  float fA[4][8], fB[4][8];
  RG_LOADA(0, fA);

  RG_STAGE(0);
  RG_LOADA(1, fB);
  lgkm0_barrier();
  RG_MFMA(fA);
  fence_barrier();

  RG_STAGE(1);
  RG_LOADA(2, fA);
  lgkm0_barrier();
  RG_MFMA(fB);
  fence_barrier();

  RG_STAGE(2);
  RG_LOADA(3, fB);
  lgkm0_barrier();
  RG_MFMA(fA);
  fence_barrier();

  RG_STAGE(3);
  lgkm0_barrier();
  RG_MFMA(fB);

#undef RG_STAGE
#undef RG_LOADA
#undef RG_MFMA

  // epilogue
#pragma unroll
  for (int ct = 0; ct < 6; ++ct) {
    int gcol = w * 96 + ct * 16 + li;
    float bv = 0.f;
    float* dp;
    int lc;
    if (gcol < 128) { bv = bias[gcol]; dp = base; lc = gcol; }
    else if (gcol < 256) { dp = mh; lc = gcol - 128; }
    else { dp = mh + (size_t)NN * HD; lc = gcol - 256; }
#pragma unroll
    for (int sub = 0; sub < 4; ++sub) {
#pragma unroll
      for (int r = 0; r < 4; ++r) {
        int node = node0 + sub * 16 + lg * 4 + r;
        if (node < NN) dp[(size_t)node * HD + lc] = acc[sub][ct][r] + bv;
      }
    }
  }
}

// ---------------- aggregation ----------------
__global__ __launch_bounds__(256) void k_aggregate(
    float* __restrict__ io, const float* __restrict__ mh,
    const int* __restrict__ row_ptr, const int* __restrict__ cnt2,
    const int* __restrict__ entries) {
  int i = blockIdx.x * 4 + (threadIdx.x >> 6);
  int l = threadIdx.x & 63;
  if (i >= NN) return;
  int rs = row_ptr[i], re = row_ptr[i + 1];
  int c0 = cnt2[i], c1 = cnt2[NN + i];
  float inv0 = 1.f / (float)(c0 > 0 ? c0 : 1);
  float inv1 = 1.f / (float)(c1 > 0 ? c1 : 1);
  float a0 = 0, a1 = 0, b0 = 0, b1 = 0;
  int e = rs;
  for (; e + 1 < re; e += 2) {
    int ent0 = entries[e], ent1 = entries[e + 1];
    const float* r0 = mh + (((size_t)(ent0 >> 20)) * NN + (ent0 & 0xFFFFF)) * HD;
    const float* r1 = mh + (((size_t)(ent1 >> 20)) * NN + (ent1 & 0xFFFFF)) * HD;
    float v00 = r0[l], v01 = r0[l + 64];
    float v10 = r1[l], v11 = r1[l + 64];
    if (ent0 >> 20) { b0 += v00; b1 += v01; } else { a0 += v00; a1 += v01; }
    if (ent1 >> 20) { b0 += v10; b1 += v11; } else { a0 += v10; a1 += v11; }
  }
  if (e < re) {
    int ent = entries[e];
    const float* r0 = mh + (((size_t)(ent >> 20)) * NN + (ent & 0xFFFFF)) * HD;
    float v0 = r0[l], v1 = r0[l + 64];
    if (ent >> 20) { b0 += v0; b1 += v1; } else { a0 += v0; a1 += v1; }
  }
  io[(size_t)i * HD + l] += a0 * inv0 + b0 * inv1;
  io[(size_t)i * HD + l + 64] += a1 * inv0 + b1 * inv1;
}

// ---------------- final linear (MFMA, in-place) ----------------
// 64 rows/block, 4 waves in 2x2: wave = 32 rows x 64 cols.
// Raw barriers + 1-deep ping-pong prefetch of the A (io) row fragments.
__global__ __launch_bounds__(256, 4) void k_cls2(
    float* __restrict__ io, const unsigned short* __restrict__ Wt,
    const float* __restrict__ b) {
  __shared__ unsigned short bt_hi[128 * 32], bt_lo[128 * 32];  // 8KB + 8KB

  const int t = threadIdx.x;
  const int node0 = blockIdx.x * 64;
  const int w = t >> 6, lane = t & 63;
  const int li = lane & 15, lg = lane >> 4;
  const int wr = w >> 1, wc = w & 1;

  int nodeA0 = node0 + wr * 32 + li; int nd0 = nodeA0 < NN ? nodeA0 : NN - 1;
  int nodeA1 = nodeA0 + 16;          int nd1 = nodeA1 < NN ? nodeA1 : NN - 1;
  const float* ap0 = io + (size_t)nd0 * HD + lg * 8;
  const float* ap1 = io + (size_t)nd1 * HD + lg * 8;

  f32x4 acc[2][4];
#pragma unroll
  for (int a = 0; a < 2; ++a)
#pragma unroll
    for (int bq = 0; bq < 4; ++bq) acc[a][bq] = (f32x4)0.f;

#define CL_STAGE(KT)                                                             \
  do {                                                                           \
    uint4 sh_[2], sl_[2];                                                        \
    _Pragma("unroll")                                                            \
    for (int j_ = 0; j_ < 2; ++j_) {                                             \
      int cid_ = t + j_ * 256;                                                   \
      int cr_ = cid_ >> 2, c_ = cid_ & 3;                                        \
      sh_[j_] = *(const uint4*)(Wt + OFF_CLS_HI + cr_ * 128 + (KT) * 32 + c_ * 8); \
      sl_[j_] = *(const uint4*)(Wt + OFF_CLS_LO + cr_ * 128 + (KT) * 32 + c_ * 8); \
    }                                                                            \
    _Pragma("unroll")                                                            \
    for (int j_ = 0; j_ < 2; ++j_) {                                             \
      int cid_ = t + j_ * 256;                                                   \
      int cr_ = cid_ >> 2, c_ = cid_ & 3;                                        \
      unsigned b_ = cr_ * 64 + ((c_ ^ ((cr_ >> 1) & 3)) << 4);                   \
      *(uint4*)((char*)bt_hi + b_) = sh_[j_];                                    \
      *(uint4*)((char*)bt_lo + b_) = sl_[j_];                                    \
    }                                                                            \
  } while (0)

#define CL_LOADA(KT, F)                                                          \
  do {                                                                           \
    _Pragma("unroll")                                                            \
    for (int j_ = 0; j_ < 8; ++j_) {                                             \
      (F)[0][j_] = ap0[(KT) * 32 + j_];                                          \
      (F)[1][j_] = ap1[(KT) * 32 + j_];                                          \
    }                                                                            \
  } while (0)

#define CL_MFMA(F)                                                               \
  do {                                                                           \
    Frag ah_[2], al_[2];                                                         \
    _Pragma("unroll")                                                            \
    for (int sub_ = 0; sub_ < 2; ++sub_)                                         \
      _Pragma("unroll")                                                          \
      for (int q_ = 0; q_ < 4; ++q_)                                             \
        cvt_pair((F)[sub_][2 * q_], (F)[sub_][2 * q_ + 1], ah_[sub_].u[q_], al_[sub_].u[q_]); \
    _Pragma("unroll")                                                            \
    for (int ct_ = 0; ct_ < 4; ++ct_) {                                          \
      int colrow_ = wc * 64 + ct_ * 16 + li;                                     \
      int byte_ = colrow_ * 64 + (lg << 4);                                      \
      byte_ ^= ((colrow_ >> 1) & 3) << 4;                                        \
      Frag bh_, bl_;                                                             \
      bh_.v = *(const uint4*)((char*)bt_hi + byte_);                             \
      bl_.v = *(const uint4*)((char*)bt_lo + byte_);                             \
      _Pragma("unroll")                                                          \
      for (int sub_ = 0; sub_ < 2; ++sub_) {                                     \
        acc[sub_][ct_] = __builtin_amdgcn_mfma_f32_16x16x32_bf16(ah_[sub_].s, bl_.s, acc[sub_][ct_], 0, 0, 0); \
        acc[sub_][ct_] = __builtin_amdgcn_mfma_f32_16x16x32_bf16(al_[sub_].s, bh_.s, acc[sub_][ct_], 0, 0, 0); \
        acc[sub_][ct_] = __builtin_amdgcn_mfma_f32_16x16x32_bf16(ah_[sub_].s, bh_.s, acc[sub_][ct_], 0, 0, 0); \
      }                                                                          \
    }                                                                            \
  } while (0)

  float fA[2][8], fB[2][8];
  CL_LOADA(0, fA);

  CL_STAGE(0);
  CL_LOADA(1, fB);
  lgkm0_barrier();
  CL_MFMA(fA);
  fence_barrier();

  CL_STAGE(1);
  CL_LOADA(2, fA);
  lgkm0_barrier();
  CL_MFMA(fB);
  fence_barrier();

  CL_STAGE(2);
  CL_LOADA(3, fB);
  lgkm0_barrier();
  CL_MFMA(fA);
  fence_barrier();

  CL_STAGE(3);
  lgkm0_barrier();
  CL_MFMA(fB);

#undef CL_STAGE
#undef CL_LOADA
#undef CL_MFMA

  __syncthreads();  // all A-reads of this block's rows done before in-place writes
#pragma unroll
  for (int ct = 0; ct < 4; ++ct) {
    int col = wc * 64 + ct * 16 + li;
    float bv = b[col];
#pragma unroll
    for (int sub = 0; sub < 2; ++sub) {
#pragma unroll
      for (int r = 0; r < 4; ++r) {
        int node = node0 + wr * 32 + sub * 16 + lg * 4 + r;
        if (node < NN) io[(size_t)node * HD + col] = acc[sub][ct][r] + bv;
      }
    }
  }
}

extern "C" void kernel_launch(void* const* d_in, const int* in_sizes, int n_in,
                              void* d_out, int out_size, void* d_ws, size_t ws_size,
                              hipStream_t stream) {
  const float* x    = (const float*)d_in[0];
  const int* ei     = (const int*)d_in[1];
  const int* et     = (const int*)d_in[2];
  const float* Wdes = (const float*)d_in[3];
  const float* bdes = (const float*)d_in[4];
  const float* Wtw  = (const float*)d_in[5];
  const float* btw  = (const float*)d_in[6];
  const float* Wnum = (const float*)d_in[7];
  const float* bnum = (const float*)d_in[8];
  const float* Wcat = (const float*)d_in[9];
  const float* bcat = (const float*)d_in[10];
  const float* Win  = (const float*)d_in[11];
  const float* bin  = (const float*)d_in[12];
  const float* pa   = (const float*)d_in[13];
  const float* root1 = (const float*)d_in[14];
  const float* rel1  = (const float*)d_in[15];
  const float* bias1 = (const float*)d_in[16];
  const float* root2 = (const float*)d_in[17];
  const float* rel2  = (const float*)d_in[18];
  const float* bias2 = (const float*)d_in[19];
  const float* Wcls  = (const float*)d_in[20];
  const float* bcls  = (const float*)d_in[21];
  float* out = (float*)d_out;

  char* p = (char*)d_ws;
  float* mh = (float*)p;      p += (size_t)2 * NN * HD * 4;   // 102.4 MB
  float* hB = (float*)p;      p += (size_t)NN * HD * 4;       // 51.2 MB
  int* row_ptr = (int*)p;     p += ((size_t)NN + 4) * 4;
  int* cnt2 = (int*)p;        p += (size_t)2 * NN * 4;
  int* fillpos = (int*)p;     p += (size_t)NN * 4;
  int* entries = (int*)p;     p += (size_t)EE * 4;
  int* bsum = (int*)p;        p += 512;
  unsigned short* Wt = (unsigned short*)p;  p += (size_t)WT_SITES * 2 * 2;

  // weight pre-convert (independent of everything else)
  k_prepw<<<(WT_SITES + 255) / 256, 256, 0, stream>>>(
      Wdes, Wtw, Wnum, Wcat, Win, root1, rel1, root2, rel2, Wcls, Wt);

  // CSR build
  hipMemsetAsync(cnt2, 0, (size_t)3 * NN * 4, stream);  // cnt2 + fillpos
  k_count<<<EE / 256, 256, 0, stream>>>(ei, et, cnt2);
  int nb = (NN + 1023) / 1024;
  k_scan1<<<nb, 256, 0, stream>>>(cnt2, row_ptr, bsum);
  k_scan2<<<1, 128, 0, stream>>>(bsum, nb);
  k_scan3<<<(NN + 1 + 255) / 256, 256, 0, stream>>>(row_ptr, bsum);
  k_fill<<<EE / 256, 256, 0, stream>>>(ei, et, row_ptr, fillpos, entries);

  const int nblk = (NN + 63) / 64;  // 1563
  // h0 -> d_out
  k_proj2<<<nblk, 256, 0, stream>>>(x, bdes, btw, bnum, bcat, bin, pa, Wt, out);
  // layer 1
  k_rgemm<<<nblk, 256, 0, stream>>>(out, Wt + OFF_L1_HI, Wt + OFF_L1_LO, bias1, hB, mh);
  k_aggregate<<<NN / 4, 256, 0, stream>>>(hB, mh, row_ptr, cnt2, entries);
  // layer 2
  k_rgemm<<<nblk, 256, 0, stream>>>(hB, Wt + OFF_L2_HI, Wt + OFF_L2_LO, bias2, out, mh);
  k_aggregate<<<NN / 4, 256, 0, stream>>>(out, mh, row_ptr, cnt2, entries);
  // classifier (MFMA, in-place)
  k_cls2<<<nblk, 256, 0, stream>>>(out, Wt, bcls);
}